// Round 9
// baseline (198.423 us; speedup 1.0000x reference)
//
#include <hip/hip_runtime.h>
#include <hip/hip_bf16.h>
#include <math.h>

#define NC_   3072
#define NT_   1024
#define NTOK  4096
#define DD    256
#define NH    8
#define HDIM  32
#define NL    2
#define FFD   1024

typedef __attribute__((ext_vector_type(8))) short short8;
typedef __attribute__((ext_vector_type(4))) float f32x4;

#if __has_builtin(__builtin_amdgcn_exp2f)
#define EXP2(x) __builtin_amdgcn_exp2f(x)
#else
#define EXP2(x) exp2f(x)
#endif

#define QSCALE 0.25503482964f   // log2(e)/sqrt(32), folded into Q at GEMM epilogue

__device__ inline float bf2f(ushort u) { return __uint_as_float(((unsigned)u) << 16); }
__device__ inline ushort f2bf(float x) {
    __hip_bfloat16 h = __float2bfloat16(x);
    return *reinterpret_cast<ushort*>(&h);
}
__device__ inline void gload16(const void* g, void* l) {
    __builtin_amdgcn_global_load_lds(
        (const __attribute__((address_space(1))) void*)g,
        (__attribute__((address_space(3))) void*)l, 16, 0, 0);
}

// ---------------- weight convert: fp32 [K][N] -> bf16 transposed [N][K], + bQKV concat ----
// packed per-layer (elements): WQKVt[768][256] | WOt 196608 | W1t 262144 | W2t 524288.
// Shared dec_W2t [256][256] appended at wbf + 2*786432 (converted on l==0 pass only).
__global__ __launch_bounds__(256) void convert_kernel(
    const float* __restrict__ WQ, const float* __restrict__ WK,
    const float* __restrict__ WV, const float* __restrict__ WO,
    const float* __restrict__ W1, const float* __restrict__ W2,
    const float* __restrict__ bQ, const float* __restrict__ bK,
    const float* __restrict__ bV, const float* __restrict__ dW2,
    ushort* __restrict__ wbf, float* __restrict__ bqkv)
{
    int l = blockIdx.y;
    int idx = blockIdx.x * 256 + threadIdx.x;
    if (idx >= 787200) {                // shared dec_W2t (l==0 only)
        if (l != 0) return;
        int i = idx - 787200;           // 0..65535
        int n = i >> 8, k = i & 255;
        wbf[(size_t)2*786432 + i] = f2bf(dW2[(size_t)k*256 + n]);
        return;
    }
    if (idx >= 786432) {
        int i = idx - 786432;           // < 768
        float bv = (i < 256) ? bQ[l*256 + i]
                 : (i < 512) ? bK[l*256 + (i - 256)]
                             : bV[l*256 + (i - 512)];
        bqkv[l*768 + i] = bv;
        return;
    }
    float v;
    if (idx < 196608) {                 // WQKVt[768][256]
        int n = idx >> 8, k = idx & 255;
        v = (n < 256) ? WQ[(size_t)(l*256 + k)*256 + n]
          : (n < 512) ? WK[(size_t)(l*256 + k)*256 + (n-256)]
                      : WV[(size_t)(l*256 + k)*256 + (n-512)];
    } else if (idx < 262144) {          // WOt[256][256]
        int i = idx - 196608, n = i >> 8, k = i & 255;
        v = WO[(size_t)(l*256 + k)*256 + n];
    } else if (idx < 524288) {          // W1t[1024][256]
        int i = idx - 262144, n = i >> 8, k = i & 255;
        v = W1[(size_t)(l*256 + k)*1024 + n];
    } else {                            // W2t[256][1024]
        int i = idx - 524288, n = i >> 10, k = i & 1023;
        v = W2[(size_t)(l*1024 + k)*256 + n];
    }
    wbf[(size_t)l*786432 + idx] = f2bf(v);
}

// ---------------- decorator stage 1: tv[m][k] = tanh(y_all[m]*W1[k]+b1[k]) bf16 ----------------
__global__ __launch_bounds__(256) void tanh_kernel(
    const float* __restrict__ y_context, const float* __restrict__ dec_W1,
    const float* __restrict__ dec_b1, ushort* __restrict__ tv)
{
    size_t base = ((size_t)blockIdx.x * 256 + threadIdx.x) * 4;
    int m = base >> 8, k = base & 255;
    float y = (m < NC_) ? y_context[m] : 0.f;
    ushort4 u;
    u.x = f2bf(tanhf(y * dec_W1[k+0] + dec_b1[k+0]));
    u.y = f2bf(tanhf(y * dec_W1[k+1] + dec_b1[k+1]));
    u.z = f2bf(tanhf(y * dec_W1[k+2] + dec_b1[k+2]));
    u.w = f2bf(tanhf(y * dec_W1[k+3] + dec_b1[k+3]));
    *(ushort4*)&tv[base] = u;
}

// ---------------- bf16 MFMA GEMM 64x64 (4 waves): WO + decorator ----------------
// mode: 0=f32, 3=bf16+relu, 5=decorator (v = c_all + w(m)*(acc+bias); Cv=c f32, Cv2=c_bf)
__global__ __launch_bounds__(256) void gemm_bf(
    const ushort* __restrict__ A, const ushort* __restrict__ Bt,
    const float* __restrict__ bias, void* __restrict__ Cv, void* __restrict__ Cv2,
    int M, int N, int K, int mode,
    const float* __restrict__ xc, const float* __restrict__ ca,
    const float* __restrict__ cb, const float* __restrict__ lk)
{
    __shared__ ushort As[64*64];   // [64 m][64 k], XOR-swizzled: byte ^= (row&7)<<4
    __shared__ ushort Bs[64*64];
    int tid = threadIdx.x, lane = tid & 63, w = tid >> 6;
    int wm = w >> 1, wn = w & 1;
    int m0 = blockIdx.y * 64, n0 = blockIdx.x * 64;
    int col = lane & 15, grp = lane >> 4;
    f32x4 acc[2][2] = {};

    for (int k0 = 0; k0 < K; k0 += 64) {
        __syncthreads();
        #pragma unroll
        for (int s = 0; s < 2; ++s) {
            int i = tid + s*256;
            int r = i >> 3, j = i & 7;
            int kb = (j*16) ^ ((r & 7) << 4);    // pre-swizzled source byte offset
            gload16((const char*)(A  + (size_t)(m0 + r)*K + k0) + kb,
                    (char*)As + s*4096 + w*1024);
            gload16((const char*)(Bt + (size_t)(n0 + r)*K + k0) + kb,
                    (char*)Bs + s*4096 + w*1024);
        }
        __syncthreads();
        #pragma unroll
        for (int kk = 0; kk < 64; kk += 32) {
            short8 a[2], b[2];
            #pragma unroll
            for (int f = 0; f < 2; ++f) {
                int ra = wm*32 + f*16 + col;
                a[f] = *(const short8*)((char*)As + ra*128 + (((kk + grp*8)*2) ^ ((ra & 7) << 4)));
                int rb = wn*32 + f*16 + col;
                b[f] = *(const short8*)((char*)Bs + rb*128 + (((kk + grp*8)*2) ^ ((rb & 7) << 4)));
            }
            #pragma unroll
            for (int fm = 0; fm < 2; ++fm)
                #pragma unroll
                for (int fn = 0; fn < 2; ++fn)
                    acc[fm][fn] = __builtin_amdgcn_mfma_f32_16x16x32_bf16(a[fm], b[fn], acc[fm][fn], 0, 0, 0);
        }
    }
    float kap = (mode == 5) ? log1pf(expf(lk[0])) : 0.f;
    #pragma unroll
    for (int fm = 0; fm < 2; ++fm) {
        #pragma unroll
        for (int fn = 0; fn < 2; ++fn) {
            int ncol = n0 + wn*32 + fn*16 + col;
            int mbase = m0 + wm*32 + fm*16 + grp*4;
            float bs = bias[ncol];
            if (mode == 5) {   // decorator epilogue
                #pragma unroll
                for (int r = 0; r < 4; ++r) {
                    int m = mbase + r;
                    float basev = (m < NC_) ? ca[(size_t)m*DD + ncol]
                                            : cb[(size_t)(m - NC_)*DD + ncol];
                    float wv = 0.f;
                    if (m < NC_) { float e = xc[m]; wv = e / (e + kap); }
                    float v = basev + wv * (acc[fm][fn][r] + bs);
                    ((float*)Cv)[(size_t)m*DD + ncol] = v;
                    ((ushort*)Cv2)[(size_t)m*DD + ncol] = f2bf(v);
                }
            } else {
                #pragma unroll
                for (int r = 0; r < 4; ++r) {
                    float v = acc[fm][fn][r] + bs;
                    if (mode == 3) v = fmaxf(v, 0.f);
                    if (mode == 0) ((float*)Cv)[(size_t)(mbase + r)*N + ncol] = v;
                    else           ((ushort*)Cv)[(size_t)(mbase + r)*N + ncol] = f2bf(v);
                }
            }
        }
    }
}

// ---------------- bf16 MFMA GEMM 128x128 (8 waves): QKV / FFN1 / FFN2 ----------------
// waves 2x4 (wm=w>>2, wn=w&3): per-wave 64x32 = 4x2 fragments, 16 MFMA/K-step.
// mode: 0=f32, 3=bf16+relu, 4=QKV split (ncol<256 -> Qh head-major scaled;
// 256..511 -> Kh at Cv+1048576; >=512 -> Cv2 = Vt transposed [n-512][M]).
__global__ __launch_bounds__(512, 4) void gemm128(
    const ushort* __restrict__ A, const ushort* __restrict__ Bt,
    const float* __restrict__ bias, void* __restrict__ Cv, void* __restrict__ Cv2,
    int M, int N, int K, int mode)
{
    __shared__ ushort As[128*64];   // [128 m][64 k], swizzle byte ^= (row&7)<<4
    __shared__ ushort Bs[128*64];
    int tid = threadIdx.x, lane = tid & 63, w = tid >> 6;
    int wm = w >> 2, wn = w & 3;
    int m0 = blockIdx.y * 128, n0 = blockIdx.x * 128;
    int col = lane & 15, grp = lane >> 4;
    f32x4 acc[4][2] = {};

    for (int k0 = 0; k0 < K; k0 += 64) {
        __syncthreads();
        #pragma unroll
        for (int s = 0; s < 2; ++s) {
            int i = tid + s*512;
            int r = i >> 3, j = i & 7;
            int kb = (j*16) ^ ((r & 7) << 4);
            gload16((const char*)(A  + (size_t)(m0 + r)*K + k0) + kb,
                    (char*)As + s*8192 + w*1024);
            gload16((const char*)(Bt + (size_t)(n0 + r)*K + k0) + kb,
                    (char*)Bs + s*8192 + w*1024);
        }
        __syncthreads();
        #pragma unroll
        for (int kk = 0; kk < 64; kk += 32) {
            short8 a[4], b[2];
            #pragma unroll
            for (int f = 0; f < 4; ++f) {
                int ra = wm*64 + f*16 + col;
                a[f] = *(const short8*)((char*)As + ra*128 + (((kk + grp*8)*2) ^ ((ra & 7) << 4)));
            }
            #pragma unroll
            for (int f = 0; f < 2; ++f) {
                int rb = wn*32 + f*16 + col;
                b[f] = *(const short8*)((char*)Bs + rb*128 + (((kk + grp*8)*2) ^ ((rb & 7) << 4)));
            }
            #pragma unroll
            for (int fm = 0; fm < 4; ++fm)
                #pragma unroll
                for (int fn = 0; fn < 2; ++fn)
                    acc[fm][fn] = __builtin_amdgcn_mfma_f32_16x16x32_bf16(a[fm], b[fn], acc[fm][fn], 0, 0, 0);
        }
    }
    #pragma unroll
    for (int fm = 0; fm < 4; ++fm) {
        #pragma unroll
        for (int fn = 0; fn < 2; ++fn) {
            int ncol = n0 + wn*32 + fn*16 + col;
            int mbase = m0 + wm*64 + fm*16 + grp*4;
            float bs = bias[ncol];
            if (mode == 4 && ncol >= 512) {          // Vt transposed
                ushort* base = (ushort*)Cv2 - (size_t)512*M;
                ushort4 u;
                u.x = f2bf(acc[fm][fn][0] + bs); u.y = f2bf(acc[fm][fn][1] + bs);
                u.z = f2bf(acc[fm][fn][2] + bs); u.w = f2bf(acc[fm][fn][3] + bs);
                *(ushort4*)(base + (size_t)ncol*M + mbase) = u;
            } else if (mode == 4) {                  // Q (scaled) / K head-major
                int cc = ncol & 255, hh = cc >> 5, hd = cc & 31;
                ushort* base = (ushort*)Cv + ((ncol < 256) ? 0u : 1048576u);
                float sc = (ncol < 256) ? QSCALE : 1.f;
                #pragma unroll
                for (int r = 0; r < 4; ++r)
                    base[((size_t)hh*M + mbase + r)*HDIM + hd] = f2bf((acc[fm][fn][r] + bs) * sc);
            } else {
                #pragma unroll
                for (int r = 0; r < 4; ++r) {
                    float v = acc[fm][fn][r] + bs;
                    if (mode == 3) v = fmaxf(v, 0.f);
                    if (mode == 0) ((float*)Cv)[(size_t)(mbase + r)*N + ncol] = v;
                    else           ((ushort*)Cv)[(size_t)(mbase + r)*N + ncol] = f2bf(v);
                }
            }
        }
    }
}

// ---------------- flash attention: 16 waves, 128 q/block, 128-key tiles, P in-register ----
// grid (NTOK/128, NH), block 1024. Wave w: q-group wq=w&7 (16 q), key-half kh=w>>3
// (64 keys/tile as 2 chunks of 32). Keys at PERMUTED physical rows (chunk*32 + hi*16 + q')
// so QK^T D-layout == PV K=32 B-frag -> P stays in registers. K rows 80B, V^T rows 272B
// (<=2-way banks). Reg-staged dbuf, 2x-unrolled loop w/ static buffers, 1 barrier/tile,
// setprio around MFMAs. Combine buffer aliases dead K/V LDS; 2-way LSE merge.
// Q pre-scaled by log2(e)/sqrt(32); softmax in exp2 domain; defer-max (THR=8).
__global__ __launch_bounds__(1024, 4) void attn_kernel(
    const ushort* __restrict__ Qh, const ushort* __restrict__ Kh,
    const ushort* __restrict__ Vt, ushort* __restrict__ AO)
{
    __shared__ __align__(16) char smem[37888];   // Ks[2][128*80]=20480 | Vs[2][32*272]=17408
    __shared__ float cml[16][2][16];
    int tid = threadIdx.x;
    int w = tid >> 6, lane = tid & 63;
    int q = lane & 15, g = lane >> 4;
    int wq = w & 7, kh = w >> 3;
    int h = blockIdx.y;
    int q0 = blockIdx.x * 128;

    // Q B-frag (pre-scaled, head-major)
    short8 bq = *(const short8*)&Qh[((size_t)h*NTOK + q0 + wq*16 + q)*HDIM + g*8];

    f32x4 acc0 = {0.f,0.f,0.f,0.f}, acc1 = {0.f,0.f,0.f,0.f};
    float mC = -INFINITY, lsum = 0.f;
    const f32x4 z = {0.f,0.f,0.f,0.f};
    const int is_tgt = (q0 >= NC_);
    const int nk = is_tgt ? NC_ : NTOK;
    const int nt = nk >> 7;              // 24 or 32 tiles (even)

    // staging: tid<512 -> K (128 rows x 64B, permuted rows); tid>=512 -> V (32 x 256B)
    const ushort* src0;
    char *dA, *dB;
    size_t sstep;
    if (tid < 512) {
        int kk = tid >> 2, sl = tid & 3;
        int k32 = kk & 31, ch = kk >> 5;
        int prow = ch*32 + ((k32 >> 2) & 1)*16 + (((k32 >> 3) << 2) | (k32 & 3));
        src0 = Kh + ((size_t)h*NTOK + kk)*HDIM + sl*8;
        dA = smem + prow*80 + sl*16;
        dB = dA + 10240;
        sstep = (size_t)128*HDIM;
    } else {
        int sidx = tid - 512;
        int d = sidx >> 4, sl = sidx & 15;
        src0 = Vt + (size_t)(h*HDIM + d)*NTOK + sl*8;
        dA = smem + 20480 + d*272 + sl*16;
        dB = dA + 8704;
        sstep = 128;
    }
    short8 sA, sB;
    {
        short8 r0 = *(const short8*)src0;            // tile 0
        *(short8*)dA = r0;
        sA = *(const short8*)(src0 + sstep);         // prefetch tile 1 (nt>=2 always)
    }
    asm volatile("s_waitcnt lgkmcnt(0)" ::: "memory");
    __builtin_amdgcn_s_barrier();
    __builtin_amdgcn_sched_barrier(0);

    // compute-body macro: X = buffer (0/1), compile-time
#define ATTN_TILE(X)                                                                     \
    {                                                                                    \
        const char* kb = smem + X*10240 + (kh*64 + q)*80 + g*16;                         \
        const char* vb = smem + 20480 + X*8704 + q*272 + kh*128 + g*16;                  \
        short8 ka0 = *(const short8*)(kb);                                               \
        short8 ka1 = *(const short8*)(kb + 16*80);                                       \
        short8 ka2 = *(const short8*)(kb + 32*80);                                       \
        short8 ka3 = *(const short8*)(kb + 48*80);                                       \
        __builtin_amdgcn_s_setprio(1);                                                   \
        f32x4 st0 = __builtin_amdgcn_mfma_f32_16x16x32_bf16(ka0, bq, z, 0, 0, 0);        \
        f32x4 st1 = __builtin_amdgcn_mfma_f32_16x16x32_bf16(ka1, bq, z, 0, 0, 0);        \
        f32x4 st2 = __builtin_amdgcn_mfma_f32_16x16x32_bf16(ka2, bq, z, 0, 0, 0);        \
        f32x4 st3 = __builtin_amdgcn_mfma_f32_16x16x32_bf16(ka3, bq, z, 0, 0, 0);        \
        __builtin_amdgcn_s_setprio(0);                                                   \
        float mx = fmaxf(fmaxf(fmaxf(fmaxf(st0[0], st0[1]), fmaxf(st0[2], st0[3])),      \
                               fmaxf(fmaxf(st1[0], st1[1]), fmaxf(st1[2], st1[3]))),     \
                         fmaxf(fmaxf(fmaxf(st2[0], st2[1]), fmaxf(st2[2], st2[3])),      \
                               fmaxf(fmaxf(st3[0], st3[1]), fmaxf(st3[2], st3[3]))));    \
        if (__any(mx > mC + 8.f)) {                                                      \
            float M = mx;                                                                \
            M = fmaxf(M, __shfl_xor(M, 16, 64));                                         \
            M = fmaxf(M, __shfl_xor(M, 32, 64));                                         \
            float mCn = fmaxf(mC, M);                                                    \
            float corr = EXP2(mC - mCn);                                                 \
            acc0 *= corr; acc1 *= corr; lsum *= corr;                                    \
            mC = mCn;                                                                    \
        }                                                                                \
        float p0 = EXP2(st0[0] - mC), p1 = EXP2(st0[1] - mC);                            \
        float p2 = EXP2(st0[2] - mC), p3 = EXP2(st0[3] - mC);                            \
        float p4 = EXP2(st1[0] - mC), p5 = EXP2(st1[1] - mC);                            \
        float p6 = EXP2(st1[2] - mC), p7 = EXP2(st1[3] - mC);                            \
        float p8 = EXP2(st2[0] - mC), p9 = EXP2(st2[1] - mC);                            \
        float pa = EXP2(st2[2] - mC), pb = EXP2(st2[3] - mC);                            \
        float pc = EXP2(st3[0] - mC), pd = EXP2(st3[1] - mC);                            \
        float pe = EXP2(st3[2] - mC), pff = EXP2(st3[3] - mC);                           \
        lsum += (((p0 + p1) + (p2 + p3)) + ((p4 + p5) + (p6 + p7)))                      \
              + (((p8 + p9) + (pa + pb)) + ((pc + pd) + (pe + pff)));                    \
        short8 pf0, pf1;                                                                 \
        pf0[0] = (short)f2bf(p0); pf0[1] = (short)f2bf(p1);                              \
        pf0[2] = (short)f2bf(p2); pf0[3] = (short)f2bf(p3);                              \
        pf0[4] = (short)f2bf(p4); pf0[5] = (short)f2bf(p5);                              \
        pf0[6] = (short)f2bf(p6); pf0[7] = (short)f2bf(p7);                              \
        pf1[0] = (short)f2bf(p8); pf1[1] = (short)f2bf(p9);                              \
        pf1[2] = (short)f2bf(pa); pf1[3] = (short)f2bf(pb);                              \
        pf1[4] = (short)f2bf(pc); pf1[5] = (short)f2bf(pd);                              \
        pf1[6] = (short)f2bf(pe); pf1[7] = (short)f2bf(pff);                             \
        short8 va00 = *(const short8*)(vb);                                              \
        short8 va10 = *(const short8*)(vb + 16*272);                                     \
        short8 va01 = *(const short8*)(vb + 64);                                         \
        short8 va11 = *(const short8*)(vb + 16*272 + 64);                                \
        __builtin_amdgcn_s_setprio(1);                                                   \
        acc0 = __builtin_amdgcn_mfma_f32_16x16x32_bf16(va00, pf0, acc0, 0, 0, 0);        \
        acc1 = __builtin_amdgcn_mfma_f32_16x16x32_bf16(va10, pf0, acc1, 0, 0, 0);        \
        acc0 = __builtin_amdgcn_mfma_f32_16x16x32_bf16(va01, pf1, acc0, 0, 0, 0);        \
        acc1 = __builtin_amdgcn_mfma_f32_16x16x32_bf16(va11, pf1, acc1, 0, 0, 0);        \
        __builtin_amdgcn_s_setprio(0);                                                   \
    }

    for (int t = 0; t < nt; t += 2) {
        // phase A: stage tile t+1 -> buf1, prefetch t+2, compute buf0 (tile t)
        *(short8*)dB = sA;
        if (t + 2 < nt) sB = *(const short8*)(src0 + (size_t)(t+2)*sstep);
        ATTN_TILE(0)
        asm volatile("s_waitcnt lgkmcnt(0)" ::: "memory");
        __builtin_amdgcn_s_barrier();
        __builtin_amdgcn_sched_barrier(0);
        // phase B: stage tile t+2 -> buf0, prefetch t+3, compute buf1 (tile t+1)
        if (t + 2 < nt) {
            *(short8*)dA = sB;
            if (t + 3 < nt) sA = *(const short8*)(src0 + (size_t)(t+3)*sstep);
        }
        ATTN_TILE(1)
        if (t + 2 < nt) {
            asm volatile("s_waitcnt lgkmcnt(0)" ::: "memory");
            __builtin_amdgcn_s_barrier();
            __builtin_amdgcn_sched_barrier(0);
        }
    }
#undef ATTN_TILE

    if (is_tgt && kh == 0) {   // self-key (structural mask), once per query (waves 0-7)
        int qg = q0 + wq*16 + q;
        short8 kv = *(const short8*)&Kh[((size_t)h*NTOK + qg)*HDIM + g*8];
        float d8 = 0.f;
        #pragma unroll
        for (int e = 0; e < 8; ++e) d8 += bf2f((ushort)bq[e]) * bf2f((ushort)kv[e]);
        d8 += __shfl_xor(d8, 16, 64);
        d8 += __shfl_xor(d8, 32, 64);    // already log2-scaled (Q pre-scaled)
        float mCn = fmaxf(mC, d8);
        float corr = EXP2(mC - mCn);
        float pp = EXP2(d8 - mCn);
        mC = mCn;
        lsum = lsum*corr + ((g == 0) ? pp : 0.f);
        acc0 *= corr; acc1 *= corr;
        #pragma unroll
        for (int r = 0; r < 4; ++r) {
            acc0[r] += pp * bf2f(Vt[(size_t)(h*HDIM + g*4 + r)*NTOK + qg]);
            acc1[r] += pp * bf2f(Vt[(size_t)(h*HDIM + 16 + g*4 + r)*NTOK + qg]);
        }
    }

    lsum += __shfl_xor(lsum, 16, 64);
    lsum += __shfl_xor(lsum, 32, 64);
    __syncthreads();                      // K/V tiles dead; reuse smem as combine buffer
    float* cacc = (float*)smem;           // [16][32][17]
    #pragma unroll
    for (int r = 0; r < 4; ++r) {
        cacc[(w*32 + g*4 + r)*17 + q]      = acc0[r];
        cacc[(w*32 + 16 + g*4 + r)*17 + q] = acc1[r];
    }
    if (g == 0) { cml[w][0][q] = mC; cml[w][1][q] = lsum; }
    __syncthreads();

    if (w < 8) {   // 2-way LSE merge over key-halves {w, w+8}; q-group w
        float m0_ = cml[w][0][q], m1_ = cml[w+8][0][q];
        float l0 = cml[w][1][q],  l1 = cml[w+8][1][q];
        float M = fmaxf(m0_, m1_);
        float f0 = EXP2(m0_ - M), f1 = EXP2(m1_ - M);
        float inv = 1.f / (l0*f0 + l1*f1);
        ushort* dst = AO + (size_t)(q0 + w*16 + q)*DD + h*HDIM;
        ushort4 o0, o1;
        #pragma unroll
        for (int r = 0; r < 4; ++r) {
            int e0 = g*4 + r, e1 = 16 + g*4 + r;
            float O0 = cacc[(w*32+e0)*17+q]*f0 + cacc[((w+8)*32+e0)*17+q]*f1;
            float O1 = cacc[(w*32+e1)*17+q]*f0 + cacc[((w+8)*32+e1)*17+q]*f1;
            ((ushort*)&o0)[r] = f2bf(O0 * inv);
            ((ushort*)&o1)[r] = f2bf(O1 * inv);
        }
        *(ushort4*)(dst + g*4) = o0;
        *(ushort4*)(dst + 16 + g*4) = o1;
    }
}

// ---------------- layernorm: c = LN(c + delta)*g + b ; + bf16 copy ----------------
__global__ __launch_bounds__(256) void ln_kernel(
    float* __restrict__ c, const float* __restrict__ delta,
    const float* __restrict__ g, const float* __restrict__ b, ushort* __restrict__ cbf)
{
    int tid = threadIdx.x;
    int wid = tid >> 6, lane = tid & 63;
    int row = blockIdx.x * 4 + wid;
    float4 x  = *(const float4*)&c[(size_t)row*DD + lane*4];
    float4 dl = *(const float4*)&delta[(size_t)row*DD + lane*4];
    x.x += dl.x; x.y += dl.y; x.z += dl.z; x.w += dl.w;
    float s = x.x + x.y + x.z + x.w;
    #pragma unroll
    for (int off = 1; off < 64; off <<= 1) s += __shfl_xor(s, off, 64);
    float mean = s * (1.f/DD);
    float dx = x.x-mean, dy = x.y-mean, dz = x.z-mean, dw = x.w-mean;
    float v = dx*dx + dy*dy + dz*dz + dw*dw;
    #pragma unroll
    for (int off = 1; off < 64; off <<= 1) v += __shfl_xor(v, off, 64);
    float rstd = rsqrtf(v*(1.f/DD) + 1e-5f);
    float4 g4 = *(const float4*)&g[lane*4];
    float4 b4 = *(const float4*)&b[lane*4];
    float4 o;
    o.x = dx*rstd*g4.x + b4.x;
    o.y = dy*rstd*g4.y + b4.y;
    o.z = dz*rstd*g4.z + b4.z;
    o.w = dw*rstd*g4.w + b4.w;
    *(float4*)&c[(size_t)row*DD + lane*4] = o;
    ushort4 u;
    u.x = f2bf(o.x); u.y = f2bf(o.y); u.z = f2bf(o.z); u.w = f2bf(o.w);
    *(ushort4*)&cbf[(size_t)row*DD + lane*4] = u;
}

// ---------------- head: out = exp(c_tgt @ out_W + out_b) * exposure ----------------
__global__ __launch_bounds__(256) void out_kernel(
    const float* __restrict__ c, const float* __restrict__ out_W,
    const float* __restrict__ out_b, const float* __restrict__ exposure_target,
    float* __restrict__ out)
{
    int tid = threadIdx.x;
    int wid = tid >> 6, lane = tid & 63;
    int r = blockIdx.x * 4 + wid;
    float4 cv = *(const float4*)&c[(size_t)(NC_ + r)*DD + lane*4];
    float4 wv = *(const float4*)&out_W[lane*4];
    float s = cv.x*wv.x + cv.y*wv.y + cv.z*wv.z + cv.w*wv.w;
    #pragma unroll
    for (int off = 1; off < 64; off <<= 1) s += __shfl_xor(s, off, 64);
    if (lane == 0) out[r] = expf(s + out_b[0]) * exposure_target[r];
}

extern "C" void kernel_launch(void* const* d_in, const int* in_sizes, int n_in,
                              void* d_out, int out_size, void* d_ws, size_t ws_size,
                              hipStream_t stream) {
    const float* c_ctx            = (const float*)d_in[0];
    const float* c_tgt            = (const float*)d_in[1];
    const float* y_context        = (const float*)d_in[2];
    const float* exposure_context = (const float*)d_in[3];
    const float* exposure_target  = (const float*)d_in[4];
    const float* dec_W1           = (const float*)d_in[5];
    const float* dec_b1           = (const float*)d_in[6];
    const float* dec_W2           = (const float*)d_in[7];
    const float* dec_b2           = (const float*)d_in[8];
    const float* log_kappa        = (const float*)d_in[9];
    const float* WQ               = (const float*)d_in[10];
    const float* bQ               = (const float*)d_in[11];
    const float* WK               = (const float*)d_in[12];
    const float* bK               = (const float*)d_in[13];
    const float* WV               = (const float*)d_in[14];
    const float* bV               = (const float*)d_in[15];
    const float* WO               = (const float*)d_in[16];
    const float* bO               = (const float*)d_in[17];
    const float* ln1_g            = (const float*)d_in[18];
    const float* ln1_b            = (const float*)d_in[19];
    const float* ln2_g            = (const float*)d_in[20];
    const float* ln2_b            = (const float*)d_in[21];
    const float* ffn_W1           = (const float*)d_in[22];
    const float* ffn_b1           = (const float*)d_in[23];
    const float* ffn_W2           = (const float*)d_in[24];
    const float* ffn_b2           = (const float*)d_in[25];
    const float* out_W            = (const float*)d_in[26];
    const float* out_b            = (const float*)d_in[27];
    float* out = (float*)d_out;

    float* ws = (float*)d_ws;
    float*  c    = ws;                          // 4096*256 f32
    float*  T    = ws + 1048576;                // 4096*256 f32
    ushort* ub   = (ushort*)(ws + 2097152);
    ushort* c_bf = ub;                          // 4096*256 bf16
    ushort* Qh   = ub + 1048576;                // [8][4096][32] bf16, pre-scaled
    ushort* Khb  = ub + 2097152;                // [8][4096][32] bf16 (= Qh + 1048576)
    ushort* Vt   = ub + 3145728;                // [256][4096] bf16 (V transposed)
    ushort* AO   = ub + 4194304;                // 4096*256 bf16
    ushort* wbf  = ub + 5242880;                // 2*786432 bf16 weights + dec_W2t 65536
    ushort* wdec = wbf + 1572864;               // dec_W2t [256][256]
    float*  bqkv = (float*)(ub + 6881280);      // 2*768 f32
    ushort* tv   = AO;                          // 4096*256 bf16, dead after gemm5
    ushort* Hd   = Qh;                          // 4096*1024 bf16, aliases Qh..AO (dead then)

    convert_kernel<<<dim3(3331, 2), 256, 0, stream>>>(WQ, WK, WV, WO, ffn_W1, ffn_W2,
                                                      bQ, bK, bV, dec_W2, wbf, bqkv);
    tanh_kernel<<<1024, 256, 0, stream>>>(y_context, dec_W1, dec_b1, tv);
    gemm_bf<<<dim3(4, 64), 256, 0, stream>>>(tv, wdec, dec_b2, c, c_bf, NTOK, DD, DD, 5,
                                             exposure_context, c_ctx, c_tgt, log_kappa);
    for (int l = 0; l < NL; ++l) {
        ushort* wl = wbf + (size_t)l*786432;
        gemm128<<<dim3(6, 32), 512, 0, stream>>>(c_bf, wl, bqkv + l*768, Qh, Vt, NTOK, 768, DD, 4);
        attn_kernel<<<dim3(NTOK/128, NH), 1024, 0, stream>>>(Qh, Khb, Vt, AO);
        gemm_bf<<<dim3(4, 64),  256, 0, stream>>>(AO,   wl + 196608, bO + l*DD,      T,  nullptr, NTOK, DD, DD, 0,
                                                  nullptr, nullptr, nullptr, nullptr);
        ln_kernel<<<NTOK/4, 256, 0, stream>>>(c, T, ln1_g + l*DD, ln1_b + l*DD, c_bf);
        gemm128<<<dim3(8, 32), 512, 0, stream>>>(c_bf, wl + 262144, ffn_b1 + l*FFD, Hd, nullptr, NTOK, FFD, DD, 3);
        gemm128<<<dim3(2, 32), 512, 0, stream>>>(Hd,   wl + 524288, ffn_b2 + l*DD,  T,  nullptr, NTOK, DD, FFD, 0);
        ln_kernel<<<NTOK/4, 256, 0, stream>>>(c, T, ln2_g + l*DD, ln2_b + l*DD, c_bf);
    }
    out_kernel<<<NT_/4, 256, 0, stream>>>(c, out_W, out_b, exposure_target, out);
}

// Round 10
// 180.847 us; speedup vs baseline: 1.0972x; 1.0972x over previous
//
#include <hip/hip_runtime.h>
#include <hip/hip_bf16.h>
#include <math.h>

#define NC_   3072
#define NT_   1024
#define NTOK  4096
#define DD    256
#define NH    8
#define HDIM  32
#define NL    2
#define FFD   1024

typedef __attribute__((ext_vector_type(8))) short short8;
typedef __attribute__((ext_vector_type(4))) float f32x4;

#if __has_builtin(__builtin_amdgcn_exp2f)
#define EXP2(x) __builtin_amdgcn_exp2f(x)
#else
#define EXP2(x) exp2f(x)
#endif

#define QSCALE 0.25503482964f   // log2(e)/sqrt(32), folded into Q at GEMM epilogue

__device__ inline float bf2f(ushort u) { return __uint_as_float(((unsigned)u) << 16); }
__device__ inline ushort f2bf(float x) {
    __hip_bfloat16 h = __float2bfloat16(x);
    return *reinterpret_cast<ushort*>(&h);
}
__device__ inline void gload16(const void* g, void* l) {
    __builtin_amdgcn_global_load_lds(
        (const __attribute__((address_space(1))) void*)g,
        (__attribute__((address_space(3))) void*)l, 16, 0, 0);
}

// ---------------- weight convert + tanh stage (fused) ----------------
// packed per-layer (elements): WQKVt[768][256] | WOt 196608 | W1t 262144 | W2t 524288.
// idx>=787200 (l==0): shared dec_W2t. idx>=852736 (l==0): tv[m][k]=tanh(y*W1+b1) bf16.
__global__ __launch_bounds__(256) void convert_kernel(
    const float* __restrict__ WQ, const float* __restrict__ WK,
    const float* __restrict__ WV, const float* __restrict__ WO,
    const float* __restrict__ W1, const float* __restrict__ W2,
    const float* __restrict__ bQ, const float* __restrict__ bK,
    const float* __restrict__ bV, const float* __restrict__ dW2,
    const float* __restrict__ y_context, const float* __restrict__ dec_W1,
    const float* __restrict__ dec_b1, ushort* __restrict__ tv,
    ushort* __restrict__ wbf, float* __restrict__ bqkv)
{
    int l = blockIdx.y;
    int idx = blockIdx.x * 256 + threadIdx.x;
    if (idx >= 852736) {                // tanh region (l==0 only)
        if (l != 0) return;
        int i2 = idx - 852736;          // 0..262143
        int m = i2 >> 6, k = (i2 & 63) * 4;
        float y = (m < NC_) ? y_context[m] : 0.f;
        ushort4 u;
        u.x = f2bf(tanhf(y * dec_W1[k+0] + dec_b1[k+0]));
        u.y = f2bf(tanhf(y * dec_W1[k+1] + dec_b1[k+1]));
        u.z = f2bf(tanhf(y * dec_W1[k+2] + dec_b1[k+2]));
        u.w = f2bf(tanhf(y * dec_W1[k+3] + dec_b1[k+3]));
        *(ushort4*)&tv[(size_t)i2 * 4] = u;
        return;
    }
    if (idx >= 787200) {                // shared dec_W2t (l==0 only)
        if (l != 0) return;
        int i = idx - 787200;           // 0..65535
        int n = i >> 8, k = i & 255;
        wbf[(size_t)2*786432 + i] = f2bf(dW2[(size_t)k*256 + n]);
        return;
    }
    if (idx >= 786432) {
        int i = idx - 786432;           // < 768
        float bv = (i < 256) ? bQ[l*256 + i]
                 : (i < 512) ? bK[l*256 + (i - 256)]
                             : bV[l*256 + (i - 512)];
        bqkv[l*768 + i] = bv;
        return;
    }
    float v;
    if (idx < 196608) {                 // WQKVt[768][256]
        int n = idx >> 8, k = idx & 255;
        v = (n < 256) ? WQ[(size_t)(l*256 + k)*256 + n]
          : (n < 512) ? WK[(size_t)(l*256 + k)*256 + (n-256)]
                      : WV[(size_t)(l*256 + k)*256 + (n-512)];
    } else if (idx < 262144) {          // WOt[256][256]
        int i = idx - 196608, n = i >> 8, k = i & 255;
        v = WO[(size_t)(l*256 + k)*256 + n];
    } else if (idx < 524288) {          // W1t[1024][256]
        int i = idx - 262144, n = i >> 8, k = i & 255;
        v = W1[(size_t)(l*256 + k)*1024 + n];
    } else {                            // W2t[256][1024]
        int i = idx - 524288, n = i >> 10, k = i & 1023;
        v = W2[(size_t)(l*1024 + k)*256 + n];
    }
    wbf[(size_t)l*786432 + idx] = f2bf(v);
}

// ---------------- bf16 MFMA GEMM 64x64 (4 waves) ----------------
// mode: 0=f32, 3=bf16+relu, 4=QKV split (ncol<256 -> Qh head-major scaled;
// 256..511 -> Kh at Cv+1048576; >=512 -> Cv2 = Vt transposed [n-512][M]),
// 5=decorator (v = c_all + w(m)*(acc+bias); Cv=c f32, Cv2=c_bf bf16)
__global__ __launch_bounds__(256) void gemm_bf(
    const ushort* __restrict__ A, const ushort* __restrict__ Bt,
    const float* __restrict__ bias, void* __restrict__ Cv, void* __restrict__ Cv2,
    int M, int N, int K, int mode,
    const float* __restrict__ xc, const float* __restrict__ ca,
    const float* __restrict__ cb, const float* __restrict__ lk)
{
    __shared__ ushort As[64*64];   // [64 m][64 k], XOR-swizzled: byte ^= (row&7)<<4
    __shared__ ushort Bs[64*64];
    int tid = threadIdx.x, lane = tid & 63, w = tid >> 6;
    int wm = w >> 1, wn = w & 1;
    int m0 = blockIdx.y * 64, n0 = blockIdx.x * 64;
    int col = lane & 15, grp = lane >> 4;
    f32x4 acc[2][2] = {};

    for (int k0 = 0; k0 < K; k0 += 64) {
        __syncthreads();
        #pragma unroll
        for (int s = 0; s < 2; ++s) {
            int i = tid + s*256;
            int r = i >> 3, j = i & 7;
            int kb = (j*16) ^ ((r & 7) << 4);    // pre-swizzled source byte offset
            gload16((const char*)(A  + (size_t)(m0 + r)*K + k0) + kb,
                    (char*)As + s*4096 + w*1024);
            gload16((const char*)(Bt + (size_t)(n0 + r)*K + k0) + kb,
                    (char*)Bs + s*4096 + w*1024);
        }
        __syncthreads();
        #pragma unroll
        for (int kk = 0; kk < 64; kk += 32) {
            short8 a[2], b[2];
            #pragma unroll
            for (int f = 0; f < 2; ++f) {
                int ra = wm*32 + f*16 + col;
                a[f] = *(const short8*)((char*)As + ra*128 + (((kk + grp*8)*2) ^ ((ra & 7) << 4)));
                int rb = wn*32 + f*16 + col;
                b[f] = *(const short8*)((char*)Bs + rb*128 + (((kk + grp*8)*2) ^ ((rb & 7) << 4)));
            }
            #pragma unroll
            for (int fm = 0; fm < 2; ++fm)
                #pragma unroll
                for (int fn = 0; fn < 2; ++fn)
                    acc[fm][fn] = __builtin_amdgcn_mfma_f32_16x16x32_bf16(a[fm], b[fn], acc[fm][fn], 0, 0, 0);
        }
    }
    float kap = (mode == 5) ? log1pf(expf(lk[0])) : 0.f;
    #pragma unroll
    for (int fm = 0; fm < 2; ++fm) {
        #pragma unroll
        for (int fn = 0; fn < 2; ++fn) {
            int ncol = n0 + wn*32 + fn*16 + col;
            int mbase = m0 + wm*32 + fm*16 + grp*4;
            float bs = bias[ncol];
            if (mode == 4 && ncol >= 512) {          // Vt transposed
                ushort* base = (ushort*)Cv2 - (size_t)512*M;
                ushort4 u;
                u.x = f2bf(acc[fm][fn][0] + bs); u.y = f2bf(acc[fm][fn][1] + bs);
                u.z = f2bf(acc[fm][fn][2] + bs); u.w = f2bf(acc[fm][fn][3] + bs);
                *(ushort4*)(base + (size_t)ncol*M + mbase) = u;
            } else if (mode == 4) {                  // Q (scaled) / K head-major
                int cc = ncol & 255, hh = cc >> 5, hd = cc & 31;
                ushort* base = (ushort*)Cv + ((ncol < 256) ? 0u : 1048576u);
                float sc = (ncol < 256) ? QSCALE : 1.f;
                #pragma unroll
                for (int r = 0; r < 4; ++r)
                    base[((size_t)hh*M + mbase + r)*HDIM + hd] = f2bf((acc[fm][fn][r] + bs) * sc);
            } else if (mode == 5) {                  // decorator epilogue
                #pragma unroll
                for (int r = 0; r < 4; ++r) {
                    int m = mbase + r;
                    float basev = (m < NC_) ? ca[(size_t)m*DD + ncol]
                                            : cb[(size_t)(m - NC_)*DD + ncol];
                    float wv = 0.f;
                    if (m < NC_) { float e = xc[m]; wv = e / (e + kap); }
                    float v = basev + wv * (acc[fm][fn][r] + bs);
                    ((float*)Cv)[(size_t)m*DD + ncol] = v;
                    ((ushort*)Cv2)[(size_t)m*DD + ncol] = f2bf(v);
                }
            } else {
                #pragma unroll
                for (int r = 0; r < 4; ++r) {
                    float v = acc[fm][fn][r] + bs;
                    if (mode == 3) v = fmaxf(v, 0.f);
                    if (mode == 0) ((float*)Cv)[(size_t)(mbase + r)*N + ncol] = v;
                    else           ((ushort*)Cv)[(size_t)(mbase + r)*N + ncol] = f2bf(v);
                }
            }
        }
    }
}

// ---------------- flash attention: 16 waves, 64 q/block, 128-key tiles, P in-register ----
// grid (NTOK/64, NH), block 1024. Wave w: q-group wq=w&3, key-quarter kh=w>>2 (32 keys).
// Keys at PERMUTED physical rows so QK^T D-layout == PV K=32 B-frag -> P in registers.
// lsum via ones-MFMA (accl = mfma(ones, pf, accl): sums P over all 32 wave-keys, incl.
// cross-group -> no end shfl reduce). K rows 80B, V^T rows 272B (<=2-way banks).
// Reg-staged dbuf, 1 barrier/tile, setprio, max3 trees. Combine aliases dead K/V LDS.
// Q pre-scaled by log2(e)/sqrt(32); softmax in exp2 domain; defer-max (THR=8).
__global__ __launch_bounds__(1024, 8) void attn_kernel(
    const ushort* __restrict__ Qh, const ushort* __restrict__ Kh,
    const ushort* __restrict__ Vt, ushort* __restrict__ AO)
{
    __shared__ __align__(16) char smem[37888];   // Ks[2][128*80]=20480 | Vs[2][32*272]=17408
    __shared__ float cml[16][2][16];
    int tid = threadIdx.x;
    int w = tid >> 6, lane = tid & 63;
    int q = lane & 15, g = lane >> 4;
    int wq = w & 3, kh = w >> 2;
    int h = blockIdx.y;
    int q0 = blockIdx.x * 64;

    // Q B-frag (pre-scaled, head-major)
    short8 bq = *(const short8*)&Qh[((size_t)h*NTOK + q0 + wq*16 + q)*HDIM + g*8];
    short8 ones;
    #pragma unroll
    for (int e = 0; e < 8; ++e) ones[e] = (short)0x3F80;   // bf16(1.0)

    f32x4 acc0 = {0.f,0.f,0.f,0.f}, acc1 = {0.f,0.f,0.f,0.f};
    f32x4 accl = {0.f,0.f,0.f,0.f};
    float mC = -INFINITY;
    const f32x4 z = {0.f,0.f,0.f,0.f};
    const int is_tgt = (q0 >= NC_);
    const int nk = is_tgt ? NC_ : NTOK;
    const int nt = nk >> 7;              // 24 or 32 tiles

    // staging: tid<512 -> K (128 rows x 64B, permuted rows); tid>=512 -> V (32 x 256B)
    const ushort* src0;
    char *dstA, *dstB;
    size_t sstep;
    if (tid < 512) {
        int kk = tid >> 2, sl = tid & 3;
        int k32 = kk & 31, ch = kk >> 5;
        int prow = ch*32 + ((k32 >> 2) & 1)*16 + (((k32 >> 3) << 2) | (k32 & 3));
        src0 = Kh + ((size_t)h*NTOK + kk)*HDIM + sl*8;
        dstA = smem + prow*80 + sl*16;
        dstB = dstA + 10240;
        sstep = (size_t)128*HDIM;
    } else {
        int sidx = tid - 512;
        int d = sidx >> 4, sl = sidx & 15;
        src0 = Vt + (size_t)(h*HDIM + d)*NTOK + sl*8;
        dstA = smem + 20480 + d*272 + sl*16;
        dstB = dstA + 8704;
        sstep = 128;
    }
    short8 sreg = {};
    {
        short8 r0 = *(const short8*)src0;            // tile 0
        *(short8*)dstA = r0;
        if (nt > 1) sreg = *(const short8*)(src0 + sstep);   // prefetch tile 1
    }
    asm volatile("s_waitcnt lgkmcnt(0)" ::: "memory");
    __builtin_amdgcn_s_barrier();
    __builtin_amdgcn_sched_barrier(0);

    const char* kb0 = smem + (kh*32 + q)*80 + g*16;        // physical rows q, 16+q
    const char* vb0 = smem + 20480 + q*272 + kh*64 + g*16;
    const char* vb1 = vb0 + 16*272;

    for (int t = 0; t < nt; ++t) {
        int cur = t & 1;
        if (t + 1 < nt) {
            *(short8*)(cur ? dstA : dstB) = sreg;    // write next buffer
            if (t + 2 < nt) sreg = *(const short8*)(src0 + (size_t)(t+2)*sstep);
        }
        const char* kb = kb0 + cur*10240;
        short8 ka0 = *(const short8*)(kb);
        short8 ka1 = *(const short8*)(kb + 16*80);
        __builtin_amdgcn_s_setprio(1);
        f32x4 st0 = __builtin_amdgcn_mfma_f32_16x16x32_bf16(ka0, bq, z, 0, 0, 0);
        f32x4 st1 = __builtin_amdgcn_mfma_f32_16x16x32_bf16(ka1, bq, z, 0, 0, 0);
        __builtin_amdgcn_s_setprio(0);
        // max of 8 via max3 (fmaxf triples fuse to v_max3_f32)
        float mx = fmaxf(fmaxf(fmaxf(st0[0], st0[1]), st0[2]),
                   fmaxf(fmaxf(fmaxf(st0[3], st1[0]), st1[1]),
                         fmaxf(st1[2], st1[3])));
        if (__any(mx > mC + 8.f)) {      // deferred rescale (rare)
            float M = mx;
            M = fmaxf(M, __shfl_xor(M, 16, 64));
            M = fmaxf(M, __shfl_xor(M, 32, 64));
            float mCn = fmaxf(mC, M);
            float corr = EXP2(mC - mCn);
            acc0 *= corr; acc1 *= corr; accl *= corr;
            mC = mCn;
        }
        float p0 = EXP2(st0[0] - mC), p1 = EXP2(st0[1] - mC);
        float p2 = EXP2(st0[2] - mC), p3 = EXP2(st0[3] - mC);
        float p4 = EXP2(st1[0] - mC), p5 = EXP2(st1[1] - mC);
        float p6 = EXP2(st1[2] - mC), p7 = EXP2(st1[3] - mC);
        short8 pf;
        pf[0] = (short)f2bf(p0); pf[1] = (short)f2bf(p1);
        pf[2] = (short)f2bf(p2); pf[3] = (short)f2bf(p3);
        pf[4] = (short)f2bf(p4); pf[5] = (short)f2bf(p5);
        pf[6] = (short)f2bf(p6); pf[7] = (short)f2bf(p7);
        short8 va0 = *(const short8*)(vb0 + cur*8704);
        short8 va1 = *(const short8*)(vb1 + cur*8704);
        __builtin_amdgcn_s_setprio(1);
        acc0 = __builtin_amdgcn_mfma_f32_16x16x32_bf16(va0, pf, acc0, 0, 0, 0);
        acc1 = __builtin_amdgcn_mfma_f32_16x16x32_bf16(va1, pf, acc1, 0, 0, 0);
        accl = __builtin_amdgcn_mfma_f32_16x16x32_bf16(ones, pf, accl, 0, 0, 0);
        __builtin_amdgcn_s_setprio(0);
        if (t + 1 < nt) {
            asm volatile("s_waitcnt lgkmcnt(0)" ::: "memory");
            __builtin_amdgcn_s_barrier();
            __builtin_amdgcn_sched_barrier(0);
        }
    }

    float lsum = accl[0];   // full sum over this wave's keys (cross-group via MFMA)

    if (is_tgt && kh == 0) {   // self-key (structural mask), once per query
        int qg = q0 + wq*16 + q;
        short8 kv = *(const short8*)&Kh[((size_t)h*NTOK + qg)*HDIM + g*8];
        float d8 = 0.f;
        #pragma unroll
        for (int e = 0; e < 8; ++e) d8 += bf2f((ushort)bq[e]) * bf2f((ushort)kv[e]);
        d8 += __shfl_xor(d8, 16, 64);
        d8 += __shfl_xor(d8, 32, 64);    // already log2-scaled (Q pre-scaled)
        float mCn = fmaxf(mC, d8);
        float corr = EXP2(mC - mCn);
        float pp = EXP2(d8 - mCn);
        mC = mCn;
        lsum = lsum*corr + pp;
        acc0 *= corr; acc1 *= corr;
        #pragma unroll
        for (int r = 0; r < 4; ++r) {
            acc0[r] += pp * bf2f(Vt[(size_t)(h*HDIM + g*4 + r)*NTOK + qg]);
            acc1[r] += pp * bf2f(Vt[(size_t)(h*HDIM + 16 + g*4 + r)*NTOK + qg]);
        }
    }

    __syncthreads();                      // K/V tiles dead; reuse smem as combine buffer
    float* cacc = (float*)smem;           // [16][32][17]
    #pragma unroll
    for (int r = 0; r < 4; ++r) {
        cacc[(w*32 + g*4 + r)*17 + q]      = acc0[r];
        cacc[(w*32 + 16 + g*4 + r)*17 + q] = acc1[r];
    }
    if (g == 0) { cml[w][0][q] = mC; cml[w][1][q] = lsum; }
    __syncthreads();

    if (w < 4) {   // 4-way LSE merge over key-quarters {w, w+4, w+8, w+12}; q-group w
        float m0_ = cml[w][0][q],    m1_ = cml[w+4][0][q];
        float m2_ = cml[w+8][0][q],  m3_ = cml[w+12][0][q];
        float l0 = cml[w][1][q],     l1 = cml[w+4][1][q];
        float l2 = cml[w+8][1][q],   l3 = cml[w+12][1][q];
        float M = fmaxf(fmaxf(m0_, m1_), fmaxf(m2_, m3_));
        float f0 = EXP2(m0_ - M), f1 = EXP2(m1_ - M), f2 = EXP2(m2_ - M), f3 = EXP2(m3_ - M);
        float inv = 1.f / (l0*f0 + l1*f1 + l2*f2 + l3*f3);
        ushort* dst = AO + (size_t)(q0 + w*16 + q)*DD + h*HDIM;
        ushort4 o0, o1;
        #pragma unroll
        for (int r = 0; r < 4; ++r) {
            int e0 = g*4 + r, e1 = 16 + g*4 + r;
            float O0 = cacc[(w*32+e0)*17+q]*f0 + cacc[((w+4)*32+e0)*17+q]*f1
                     + cacc[((w+8)*32+e0)*17+q]*f2 + cacc[((w+12)*32+e0)*17+q]*f3;
            float O1 = cacc[(w*32+e1)*17+q]*f0 + cacc[((w+4)*32+e1)*17+q]*f1
                     + cacc[((w+8)*32+e1)*17+q]*f2 + cacc[((w+12)*32+e1)*17+q]*f3;
            ((ushort*)&o0)[r] = f2bf(O0 * inv);
            ((ushort*)&o1)[r] = f2bf(O1 * inv);
        }
        *(ushort4*)(dst + g*4) = o0;
        *(ushort4*)(dst + 16 + g*4) = o1;
    }
}

// ---------------- layernorm: c = LN(c + delta)*g + b ; + bf16 copy; optional head ----
// If ow != nullptr (final LN): for target rows also out = exp(dot(c,out_W)+out_b)*expo.
__global__ __launch_bounds__(256) void ln_kernel(
    float* __restrict__ c, const float* __restrict__ delta,
    const float* __restrict__ g, const float* __restrict__ b, ushort* __restrict__ cbf,
    const float* __restrict__ ow, const float* __restrict__ ob,
    const float* __restrict__ expo, float* __restrict__ out)
{
    int tid = threadIdx.x;
    int wid = tid >> 6, lane = tid & 63;
    int row = blockIdx.x * 4 + wid;
    float4 x  = *(const float4*)&c[(size_t)row*DD + lane*4];
    float4 dl = *(const float4*)&delta[(size_t)row*DD + lane*4];
    x.x += dl.x; x.y += dl.y; x.z += dl.z; x.w += dl.w;
    float s = x.x + x.y + x.z + x.w;
    #pragma unroll
    for (int off = 1; off < 64; off <<= 1) s += __shfl_xor(s, off, 64);
    float mean = s * (1.f/DD);
    float dx = x.x-mean, dy = x.y-mean, dz = x.z-mean, dw = x.w-mean;
    float v = dx*dx + dy*dy + dz*dz + dw*dw;
    #pragma unroll
    for (int off = 1; off < 64; off <<= 1) v += __shfl_xor(v, off, 64);
    float rstd = rsqrtf(v*(1.f/DD) + 1e-5f);
    float4 g4 = *(const float4*)&g[lane*4];
    float4 b4 = *(const float4*)&b[lane*4];
    float4 o;
    o.x = dx*rstd*g4.x + b4.x;
    o.y = dy*rstd*g4.y + b4.y;
    o.z = dz*rstd*g4.z + b4.z;
    o.w = dw*rstd*g4.w + b4.w;
    *(float4*)&c[(size_t)row*DD + lane*4] = o;
    ushort4 u;
    u.x = f2bf(o.x); u.y = f2bf(o.y); u.z = f2bf(o.z); u.w = f2bf(o.w);
    *(ushort4*)&cbf[(size_t)row*DD + lane*4] = u;
    if (ow != nullptr && row >= NC_) {   // fused output head
        float4 wv = *(const float4*)&ow[lane*4];
        float ss = o.x*wv.x + o.y*wv.y + o.z*wv.z + o.w*wv.w;
        #pragma unroll
        for (int off = 1; off < 64; off <<= 1) ss += __shfl_xor(ss, off, 64);
        if (lane == 0) out[row - NC_] = expf(ss + ob[0]) * expo[row - NC_];
    }
}

extern "C" void kernel_launch(void* const* d_in, const int* in_sizes, int n_in,
                              void* d_out, int out_size, void* d_ws, size_t ws_size,
                              hipStream_t stream) {
    const float* c_ctx            = (const float*)d_in[0];
    const float* c_tgt            = (const float*)d_in[1];
    const float* y_context        = (const float*)d_in[2];
    const float* exposure_context = (const float*)d_in[3];
    const float* exposure_target  = (const float*)d_in[4];
    const float* dec_W1           = (const float*)d_in[5];
    const float* dec_b1           = (const float*)d_in[6];
    const float* dec_W2           = (const float*)d_in[7];
    const float* dec_b2           = (const float*)d_in[8];
    const float* log_kappa        = (const float*)d_in[9];
    const float* WQ               = (const float*)d_in[10];
    const float* bQ               = (const float*)d_in[11];
    const float* WK               = (const float*)d_in[12];
    const float* bK               = (const float*)d_in[13];
    const float* WV               = (const float*)d_in[14];
    const float* bV               = (const float*)d_in[15];
    const float* WO               = (const float*)d_in[16];
    const float* bO               = (const float*)d_in[17];
    const float* ln1_g            = (const float*)d_in[18];
    const float* ln1_b            = (const float*)d_in[19];
    const float* ln2_g            = (const float*)d_in[20];
    const float* ln2_b            = (const float*)d_in[21];
    const float* ffn_W1           = (const float*)d_in[22];
    const float* ffn_b1           = (const float*)d_in[23];
    const float* ffn_W2           = (const float*)d_in[24];
    const float* ffn_b2           = (const float*)d_in[25];
    const float* out_W            = (const float*)d_in[26];
    const float* out_b            = (const float*)d_in[27];
    float* out = (float*)d_out;

    float* ws = (float*)d_ws;
    float*  c    = ws;                          // 4096*256 f32
    float*  T    = ws + 1048576;                // 4096*256 f32
    ushort* ub   = (ushort*)(ws + 2097152);
    ushort* c_bf = ub;                          // 4096*256 bf16
    ushort* Qh   = ub + 1048576;                // [8][4096][32] bf16, pre-scaled
    ushort* Khb  = ub + 2097152;                // [8][4096][32] bf16 (= Qh + 1048576)
    ushort* Vt   = ub + 3145728;                // [256][4096] bf16 (V transposed)
    ushort* AO   = ub + 4194304;                // 4096*256 bf16
    ushort* wbf  = ub + 5242880;                // 2*786432 bf16 weights + dec_W2t 65536
    ushort* wdec = wbf + 1572864;               // dec_W2t [256][256]
    float*  bqkv = (float*)(ub + 6881280);      // 2*768 f32
    ushort* tv   = AO;                          // 4096*256 bf16, dead after gemm5
    ushort* Hd   = Qh;                          // 4096*1024 bf16, aliases Qh..AO (dead then)

    convert_kernel<<<dim3(4355, 2), 256, 0, stream>>>(WQ, WK, WV, WO, ffn_W1, ffn_W2,
                                                      bQ, bK, bV, dec_W2,
                                                      y_context, dec_W1, dec_b1, tv,
                                                      wbf, bqkv);
    gemm_bf<<<dim3(4, 64), 256, 0, stream>>>(tv, wdec, dec_b2, c, c_bf, NTOK, DD, DD, 5,
                                             exposure_context, c_ctx, c_tgt, log_kappa);
    for (int l = 0; l < NL; ++l) {
        ushort* wl = wbf + (size_t)l*786432;
        int last = (l == NL - 1);
        gemm_bf<<<dim3(12, 64), 256, 0, stream>>>(c_bf, wl, bqkv + l*768, Qh, Vt, NTOK, 768, DD, 4,
                                                  nullptr, nullptr, nullptr, nullptr);
        attn_kernel<<<dim3(NTOK/64, NH), 1024, 0, stream>>>(Qh, Khb, Vt, AO);
        gemm_bf<<<dim3(4, 64),  256, 0, stream>>>(AO,   wl + 196608, bO + l*DD,      T,  nullptr, NTOK, DD, DD, 0,
                                                  nullptr, nullptr, nullptr, nullptr);
        ln_kernel<<<NTOK/4, 256, 0, stream>>>(c, T, ln1_g + l*DD, ln1_b + l*DD, c_bf,
                                              nullptr, nullptr, nullptr, nullptr);
        gemm_bf<<<dim3(16, 64), 256, 0, stream>>>(c_bf, wl + 262144, ffn_b1 + l*FFD, Hd, nullptr, NTOK, FFD, DD, 3,
                                                  nullptr, nullptr, nullptr, nullptr);
        gemm_bf<<<dim3(4, 64),  256, 0, stream>>>(Hd,   wl + 524288, ffn_b2 + l*DD,  T,  nullptr, NTOK, DD, FFD, 0,
                                                  nullptr, nullptr, nullptr, nullptr);
        ln_kernel<<<NTOK/4, 256, 0, stream>>>(c, T, ln2_g + l*DD, ln2_b + l*DD, c_bf,
                                              last ? out_W : nullptr, last ? out_b : nullptr,
                                              last ? exposure_target : nullptr, last ? out : nullptr);
    }
}

// Round 11
// 153.024 us; speedup vs baseline: 1.2967x; 1.1818x over previous
//
#include <hip/hip_runtime.h>
#include <hip/hip_bf16.h>
#include <math.h>

#define NC_   3072
#define NT_   1024
#define NTOK  4096
#define DD    256
#define NH    8
#define HDIM  32
#define NL    2
#define FFD   1024

typedef __attribute__((ext_vector_type(8))) short short8;
typedef __attribute__((ext_vector_type(4))) float f32x4;

#if __has_builtin(__builtin_amdgcn_exp2f)
#define EXP2(x) __builtin_amdgcn_exp2f(x)
#else
#define EXP2(x) exp2f(x)
#endif

#define QSCALE 0.25503482964f   // log2(e)/sqrt(32), folded into Q at GEMM epilogue

__device__ inline float bf2f(ushort u) { return __uint_as_float(((unsigned)u) << 16); }
__device__ inline ushort f2bf(float x) {
    __hip_bfloat16 h = __float2bfloat16(x);
    return *reinterpret_cast<ushort*>(&h);
}
__device__ inline void gload16(const void* g, void* l) {
    __builtin_amdgcn_global_load_lds(
        (const __attribute__((address_space(1))) void*)g,
        (__attribute__((address_space(3))) void*)l, 16, 0, 0);
}

// ---------------- weight convert + tanh stage (fused) ----------------
__global__ __launch_bounds__(256) void convert_kernel(
    const float* __restrict__ WQ, const float* __restrict__ WK,
    const float* __restrict__ WV, const float* __restrict__ WO,
    const float* __restrict__ W1, const float* __restrict__ W2,
    const float* __restrict__ bQ, const float* __restrict__ bK,
    const float* __restrict__ bV, const float* __restrict__ dW2,
    const float* __restrict__ y_context, const float* __restrict__ dec_W1,
    const float* __restrict__ dec_b1, ushort* __restrict__ tv,
    ushort* __restrict__ wbf, float* __restrict__ bqkv)
{
    int l = blockIdx.y;
    int idx = blockIdx.x * 256 + threadIdx.x;
    if (idx >= 852736) {                // tanh region (l==0 only)
        if (l != 0) return;
        int i2 = idx - 852736;          // 0..262143
        int m = i2 >> 6, k = (i2 & 63) * 4;
        float y = (m < NC_) ? y_context[m] : 0.f;
        ushort4 u;
        u.x = f2bf(tanhf(y * dec_W1[k+0] + dec_b1[k+0]));
        u.y = f2bf(tanhf(y * dec_W1[k+1] + dec_b1[k+1]));
        u.z = f2bf(tanhf(y * dec_W1[k+2] + dec_b1[k+2]));
        u.w = f2bf(tanhf(y * dec_W1[k+3] + dec_b1[k+3]));
        *(ushort4*)&tv[(size_t)i2 * 4] = u;
        return;
    }
    if (idx >= 787200) {                // shared dec_W2t (l==0 only)
        if (l != 0) return;
        int i = idx - 787200;           // 0..65535
        int n = i >> 8, k = i & 255;
        wbf[(size_t)2*786432 + i] = f2bf(dW2[(size_t)k*256 + n]);
        return;
    }
    if (idx >= 786432) {
        int i = idx - 786432;           // < 768
        float bv = (i < 256) ? bQ[l*256 + i]
                 : (i < 512) ? bK[l*256 + (i - 256)]
                             : bV[l*256 + (i - 512)];
        bqkv[l*768 + i] = bv;
        return;
    }
    float v;
    if (idx < 196608) {                 // WQKVt[768][256]
        int n = idx >> 8, k = idx & 255;
        v = (n < 256) ? WQ[(size_t)(l*256 + k)*256 + n]
          : (n < 512) ? WK[(size_t)(l*256 + k)*256 + (n-256)]
                      : WV[(size_t)(l*256 + k)*256 + (n-512)];
    } else if (idx < 262144) {          // WOt[256][256]
        int i = idx - 196608, n = i >> 8, k = i & 255;
        v = WO[(size_t)(l*256 + k)*256 + n];
    } else if (idx < 524288) {          // W1t[1024][256]
        int i = idx - 262144, n = i >> 8, k = i & 255;
        v = W1[(size_t)(l*256 + k)*1024 + n];
    } else {                            // W2t[256][1024]
        int i = idx - 524288, n = i >> 10, k = i & 1023;
        v = W2[(size_t)(l*1024 + k)*256 + n];
    }
    wbf[(size_t)l*786432 + idx] = f2bf(v);
}

// ---------------- bf16 MFMA GEMM 64x64 (4 waves) ----------------
// mode: 0=f32, 3=bf16+relu, 4=QKV split, 5=decorator
__global__ __launch_bounds__(256) void gemm_bf(
    const ushort* __restrict__ A, const ushort* __restrict__ Bt,
    const float* __restrict__ bias, void* __restrict__ Cv, void* __restrict__ Cv2,
    int M, int N, int K, int mode,
    const float* __restrict__ xc, const float* __restrict__ ca,
    const float* __restrict__ cb, const float* __restrict__ lk)
{
    __shared__ ushort As[64*64];   // [64 m][64 k], XOR-swizzled: byte ^= (row&7)<<4
    __shared__ ushort Bs[64*64];
    int tid = threadIdx.x, lane = tid & 63, w = tid >> 6;
    int wm = w >> 1, wn = w & 1;
    int m0 = blockIdx.y * 64, n0 = blockIdx.x * 64;
    int col = lane & 15, grp = lane >> 4;
    f32x4 acc[2][2] = {};

    for (int k0 = 0; k0 < K; k0 += 64) {
        __syncthreads();
        #pragma unroll
        for (int s = 0; s < 2; ++s) {
            int i = tid + s*256;
            int r = i >> 3, j = i & 7;
            int kb = (j*16) ^ ((r & 7) << 4);    // pre-swizzled source byte offset
            gload16((const char*)(A  + (size_t)(m0 + r)*K + k0) + kb,
                    (char*)As + s*4096 + w*1024);
            gload16((const char*)(Bt + (size_t)(n0 + r)*K + k0) + kb,
                    (char*)Bs + s*4096 + w*1024);
        }
        __syncthreads();
        #pragma unroll
        for (int kk = 0; kk < 64; kk += 32) {
            short8 a[2], b[2];
            #pragma unroll
            for (int f = 0; f < 2; ++f) {
                int ra = wm*32 + f*16 + col;
                a[f] = *(const short8*)((char*)As + ra*128 + (((kk + grp*8)*2) ^ ((ra & 7) << 4)));
                int rb = wn*32 + f*16 + col;
                b[f] = *(const short8*)((char*)Bs + rb*128 + (((kk + grp*8)*2) ^ ((rb & 7) << 4)));
            }
            #pragma unroll
            for (int fm = 0; fm < 2; ++fm)
                #pragma unroll
                for (int fn = 0; fn < 2; ++fn)
                    acc[fm][fn] = __builtin_amdgcn_mfma_f32_16x16x32_bf16(a[fm], b[fn], acc[fm][fn], 0, 0, 0);
        }
    }
    float kap = (mode == 5) ? log1pf(expf(lk[0])) : 0.f;
    #pragma unroll
    for (int fm = 0; fm < 2; ++fm) {
        #pragma unroll
        for (int fn = 0; fn < 2; ++fn) {
            int ncol = n0 + wn*32 + fn*16 + col;
            int mbase = m0 + wm*32 + fm*16 + grp*4;
            float bs = bias[ncol];
            if (mode == 4 && ncol >= 512) {          // Vt transposed
                ushort* base = (ushort*)Cv2 - (size_t)512*M;
                ushort4 u;
                u.x = f2bf(acc[fm][fn][0] + bs); u.y = f2bf(acc[fm][fn][1] + bs);
                u.z = f2bf(acc[fm][fn][2] + bs); u.w = f2bf(acc[fm][fn][3] + bs);
                *(ushort4*)(base + (size_t)ncol*M + mbase) = u;
            } else if (mode == 4) {                  // Q (scaled) / K head-major
                int cc = ncol & 255, hh = cc >> 5, hd = cc & 31;
                ushort* base = (ushort*)Cv + ((ncol < 256) ? 0u : 1048576u);
                float sc = (ncol < 256) ? QSCALE : 1.f;
                #pragma unroll
                for (int r = 0; r < 4; ++r)
                    base[((size_t)hh*M + mbase + r)*HDIM + hd] = f2bf((acc[fm][fn][r] + bs) * sc);
            } else if (mode == 5) {                  // decorator epilogue
                #pragma unroll
                for (int r = 0; r < 4; ++r) {
                    int m = mbase + r;
                    float basev = (m < NC_) ? ca[(size_t)m*DD + ncol]
                                            : cb[(size_t)(m - NC_)*DD + ncol];
                    float wv = 0.f;
                    if (m < NC_) { float e = xc[m]; wv = e / (e + kap); }
                    float v = basev + wv * (acc[fm][fn][r] + bs);
                    ((float*)Cv)[(size_t)m*DD + ncol] = v;
                    ((ushort*)Cv2)[(size_t)m*DD + ncol] = f2bf(v);
                }
            } else {
                #pragma unroll
                for (int r = 0; r < 4; ++r) {
                    float v = acc[fm][fn][r] + bs;
                    if (mode == 3) v = fmaxf(v, 0.f);
                    if (mode == 0) ((float*)Cv)[(size_t)(mbase + r)*N + ncol] = v;
                    else           ((ushort*)Cv)[(size_t)(mbase + r)*N + ncol] = f2bf(v);
                }
            }
        }
    }
}

// ---------------- flash attention: 16 waves, 64 q/block, 128-key tiles, P in-register ----
// l2mode=0: grid (64,8,1), layer-1 behavior (q0=bx*64, keys [0,nk), final AO write).
// l2mode=1: grid (16,8,2), q0=NC+bx*64 (targets), keys [z*1536,(z+1)*1536), partial
// (m,l,unnormalized O) -> pml/pacc; self-key in z==0. Inner loop identical.
__global__ __launch_bounds__(1024, 8) void attn_kernel(
    const ushort* __restrict__ Qh, const ushort* __restrict__ Kh,
    const ushort* __restrict__ Vt, ushort* __restrict__ AO,
    float* __restrict__ pml, float* __restrict__ pacc, int l2mode)
{
    __shared__ __align__(16) char smem[37888];   // Ks[2][128*80]=20480 | Vs[2][32*272]=17408
    __shared__ float cml[16][2][16];
    int tid = threadIdx.x;
    int w = tid >> 6, lane = tid & 63;
    int q = lane & 15, g = lane >> 4;
    int wq = w & 3, kh = w >> 2;
    int h = blockIdx.y;
    int zb = blockIdx.z;
    int q0   = l2mode ? (NC_ + blockIdx.x * 64) : (blockIdx.x * 64);
    int kbeg = l2mode ? zb * 1536 : 0;
    int do_self = l2mode ? (zb == 0) : (q0 >= NC_);
    int nt = l2mode ? 12 : (((q0 >= NC_) ? NC_ : NTOK) >> 7);

    // Q B-frag (pre-scaled, head-major)
    short8 bq = *(const short8*)&Qh[((size_t)h*NTOK + q0 + wq*16 + q)*HDIM + g*8];
    short8 ones;
    #pragma unroll
    for (int e = 0; e < 8; ++e) ones[e] = (short)0x3F80;   // bf16(1.0)

    f32x4 acc0 = {0.f,0.f,0.f,0.f}, acc1 = {0.f,0.f,0.f,0.f};
    f32x4 accl = {0.f,0.f,0.f,0.f};
    float mC = -INFINITY;
    const f32x4 z = {0.f,0.f,0.f,0.f};

    // staging: tid<512 -> K (128 rows x 64B, permuted rows); tid>=512 -> V (32 x 256B)
    const ushort* src0;
    char *dstA, *dstB;
    size_t sstep;
    if (tid < 512) {
        int kk = tid >> 2, sl = tid & 3;
        int k32 = kk & 31, ch = kk >> 5;
        int prow = ch*32 + ((k32 >> 2) & 1)*16 + (((k32 >> 3) << 2) | (k32 & 3));
        src0 = Kh + ((size_t)h*NTOK + kbeg + kk)*HDIM + sl*8;
        dstA = smem + prow*80 + sl*16;
        dstB = dstA + 10240;
        sstep = (size_t)128*HDIM;
    } else {
        int sidx = tid - 512;
        int d = sidx >> 4, sl = sidx & 15;
        src0 = Vt + (size_t)(h*HDIM + d)*NTOK + kbeg + sl*8;
        dstA = smem + 20480 + d*272 + sl*16;
        dstB = dstA + 8704;
        sstep = 128;
    }
    short8 sreg = {};
    {
        short8 r0 = *(const short8*)src0;            // tile 0
        *(short8*)dstA = r0;
        if (nt > 1) sreg = *(const short8*)(src0 + sstep);   // prefetch tile 1
    }
    asm volatile("s_waitcnt lgkmcnt(0)" ::: "memory");
    __builtin_amdgcn_s_barrier();
    __builtin_amdgcn_sched_barrier(0);

    const char* kb0 = smem + (kh*32 + q)*80 + g*16;        // physical rows q, 16+q
    const char* vb0 = smem + 20480 + q*272 + kh*64 + g*16;
    const char* vb1 = vb0 + 16*272;

    for (int t = 0; t < nt; ++t) {
        int cur = t & 1;
        if (t + 1 < nt) {
            *(short8*)(cur ? dstA : dstB) = sreg;    // write next buffer
            if (t + 2 < nt) sreg = *(const short8*)(src0 + (size_t)(t+2)*sstep);
        }
        const char* kb = kb0 + cur*10240;
        short8 ka0 = *(const short8*)(kb);
        short8 ka1 = *(const short8*)(kb + 16*80);
        __builtin_amdgcn_s_setprio(1);
        f32x4 st0 = __builtin_amdgcn_mfma_f32_16x16x32_bf16(ka0, bq, z, 0, 0, 0);
        f32x4 st1 = __builtin_amdgcn_mfma_f32_16x16x32_bf16(ka1, bq, z, 0, 0, 0);
        __builtin_amdgcn_s_setprio(0);
        float mx = fmaxf(fmaxf(fmaxf(st0[0], st0[1]), st0[2]),
                   fmaxf(fmaxf(fmaxf(st0[3], st1[0]), st1[1]),
                         fmaxf(st1[2], st1[3])));
        if (__any(mx > mC + 8.f)) {      // deferred rescale (rare)
            float M = mx;
            M = fmaxf(M, __shfl_xor(M, 16, 64));
            M = fmaxf(M, __shfl_xor(M, 32, 64));
            float mCn = fmaxf(mC, M);
            float corr = EXP2(mC - mCn);
            acc0 *= corr; acc1 *= corr; accl *= corr;
            mC = mCn;
        }
        float p0 = EXP2(st0[0] - mC), p1 = EXP2(st0[1] - mC);
        float p2 = EXP2(st0[2] - mC), p3 = EXP2(st0[3] - mC);
        float p4 = EXP2(st1[0] - mC), p5 = EXP2(st1[1] - mC);
        float p6 = EXP2(st1[2] - mC), p7 = EXP2(st1[3] - mC);
        short8 pf;
        pf[0] = (short)f2bf(p0); pf[1] = (short)f2bf(p1);
        pf[2] = (short)f2bf(p2); pf[3] = (short)f2bf(p3);
        pf[4] = (short)f2bf(p4); pf[5] = (short)f2bf(p5);
        pf[6] = (short)f2bf(p6); pf[7] = (short)f2bf(p7);
        short8 va0 = *(const short8*)(vb0 + cur*8704);
        short8 va1 = *(const short8*)(vb1 + cur*8704);
        __builtin_amdgcn_s_setprio(1);
        acc0 = __builtin_amdgcn_mfma_f32_16x16x32_bf16(va0, pf, acc0, 0, 0, 0);
        acc1 = __builtin_amdgcn_mfma_f32_16x16x32_bf16(va1, pf, acc1, 0, 0, 0);
        accl = __builtin_amdgcn_mfma_f32_16x16x32_bf16(ones, pf, accl, 0, 0, 0);
        __builtin_amdgcn_s_setprio(0);
        if (t + 1 < nt) {
            asm volatile("s_waitcnt lgkmcnt(0)" ::: "memory");
            __builtin_amdgcn_s_barrier();
            __builtin_amdgcn_sched_barrier(0);
        }
    }

    float lsum = accl[0];   // full sum over this wave's keys (cross-group via MFMA)

    if (do_self && kh == 0) {   // self-key (structural mask), once per query
        int qg = q0 + wq*16 + q;
        short8 kv = *(const short8*)&Kh[((size_t)h*NTOK + qg)*HDIM + g*8];
        float d8 = 0.f;
        #pragma unroll
        for (int e = 0; e < 8; ++e) d8 += bf2f((ushort)bq[e]) * bf2f((ushort)kv[e]);
        d8 += __shfl_xor(d8, 16, 64);
        d8 += __shfl_xor(d8, 32, 64);    // already log2-scaled (Q pre-scaled)
        float mCn = fmaxf(mC, d8);
        float corr = EXP2(mC - mCn);
        float pp = EXP2(d8 - mCn);
        mC = mCn;
        lsum = lsum*corr + pp;
        acc0 *= corr; acc1 *= corr;
        #pragma unroll
        for (int r = 0; r < 4; ++r) {
            acc0[r] += pp * bf2f(Vt[(size_t)(h*HDIM + g*4 + r)*NTOK + qg]);
            acc1[r] += pp * bf2f(Vt[(size_t)(h*HDIM + 16 + g*4 + r)*NTOK + qg]);
        }
    }

    __syncthreads();                      // K/V tiles dead; reuse smem as combine buffer
    float* cacc = (float*)smem;           // [16][32][17]
    #pragma unroll
    for (int r = 0; r < 4; ++r) {
        cacc[(w*32 + g*4 + r)*17 + q]      = acc0[r];
        cacc[(w*32 + 16 + g*4 + r)*17 + q] = acc1[r];
    }
    if (g == 0) { cml[w][0][q] = mC; cml[w][1][q] = lsum; }
    __syncthreads();

    if (w < 4) {   // 4-way LSE merge over key-quarters {w, w+4, w+8, w+12}; q-group w
        float m0_ = cml[w][0][q],    m1_ = cml[w+4][0][q];
        float m2_ = cml[w+8][0][q],  m3_ = cml[w+12][0][q];
        float l0 = cml[w][1][q],     l1 = cml[w+4][1][q];
        float l2 = cml[w+8][1][q],   l3 = cml[w+12][1][q];
        float M = fmaxf(fmaxf(m0_, m1_), fmaxf(m2_, m3_));
        float f0 = EXP2(m0_ - M), f1 = EXP2(m1_ - M), f2 = EXP2(m2_ - M), f3 = EXP2(m3_ - M);
        float L = l0*f0 + l1*f1 + l2*f2 + l3*f3;
        if (!l2mode) {
            float inv = 1.f / L;
            ushort* dst = AO + (size_t)(q0 + w*16 + q)*DD + h*HDIM;
            ushort4 o0, o1;
            #pragma unroll
            for (int r = 0; r < 4; ++r) {
                int e0 = g*4 + r, e1 = 16 + g*4 + r;
                float O0 = cacc[(w*32+e0)*17+q]*f0 + cacc[((w+4)*32+e0)*17+q]*f1
                         + cacc[((w+8)*32+e0)*17+q]*f2 + cacc[((w+12)*32+e0)*17+q]*f3;
                float O1 = cacc[(w*32+e1)*17+q]*f0 + cacc[((w+4)*32+e1)*17+q]*f1
                         + cacc[((w+8)*32+e1)*17+q]*f2 + cacc[((w+12)*32+e1)*17+q]*f3;
                ((ushort*)&o0)[r] = f2bf(O0 * inv);
                ((ushort*)&o1)[r] = f2bf(O1 * inv);
            }
            *(ushort4*)(dst + g*4) = o0;
            *(ushort4*)(dst + 16 + g*4) = o1;
        } else {     // partial out: unnormalized O + (m, l)
            int qi = q0 - NC_ + w*16 + q;
            float* pa = pacc + (((size_t)zb*NH + h)*NT_ + qi)*32;
            #pragma unroll
            for (int r = 0; r < 4; ++r) {
                int e0 = g*4 + r, e1 = 16 + g*4 + r;
                pa[e0] = cacc[(w*32+e0)*17+q]*f0 + cacc[((w+4)*32+e0)*17+q]*f1
                       + cacc[((w+8)*32+e0)*17+q]*f2 + cacc[((w+12)*32+e0)*17+q]*f3;
                pa[e1] = cacc[(w*32+e1)*17+q]*f0 + cacc[((w+4)*32+e1)*17+q]*f1
                       + cacc[((w+8)*32+e1)*17+q]*f2 + cacc[((w+12)*32+e1)*17+q]*f3;
            }
            if (g == 0) {
                float* pm = pml + (((size_t)zb*NH + h)*NT_ + qi)*2;
                pm[0] = M; pm[1] = L;
            }
        }
    }
}

// ---------------- combine: 2-way LSE merge of layer-2 attn partials -> AO ----------------
__global__ __launch_bounds__(256) void combine_kernel(
    const float* __restrict__ pml, const float* __restrict__ pacc, ushort* __restrict__ AO)
{
    int item = blockIdx.x * 8 + (threadIdx.x >> 5);   // 8192 items = 8 h x 1024 q
    int d = threadIdx.x & 31;
    int hh = item >> 10, qi = item & 1023;
    size_t i0 = ((size_t)0*NH + hh)*NT_ + qi;
    size_t i1 = ((size_t)1*NH + hh)*NT_ + qi;
    float m0 = pml[i0*2], l0 = pml[i0*2+1];
    float m1 = pml[i1*2], l1 = pml[i1*2+1];
    float M = fmaxf(m0, m1);
    float f0 = EXP2(m0 - M), f1 = EXP2(m1 - M);
    float inv = 1.f / (l0*f0 + l1*f1);
    float O = pacc[i0*32 + d]*f0 + pacc[i1*32 + d]*f1;
    AO[(size_t)(NC_ + qi)*DD + hh*HDIM + d] = f2bf(O * inv);
}

// ---------------- layernorm: c = LN(c + delta)*g + b ; + bf16 copy; optional head ----
// If ow != nullptr: head fires for ALL rows (caller passes target-row base pointers).
__global__ __launch_bounds__(256) void ln_kernel(
    float* __restrict__ c, const float* __restrict__ delta,
    const float* __restrict__ g, const float* __restrict__ b, ushort* __restrict__ cbf,
    const float* __restrict__ ow, const float* __restrict__ ob,
    const float* __restrict__ expo, float* __restrict__ out)
{
    int tid = threadIdx.x;
    int wid = tid >> 6, lane = tid & 63;
    int row = blockIdx.x * 4 + wid;
    float4 x  = *(const float4*)&c[(size_t)row*DD + lane*4];
    float4 dl = *(const float4*)&delta[(size_t)row*DD + lane*4];
    x.x += dl.x; x.y += dl.y; x.z += dl.z; x.w += dl.w;
    float s = x.x + x.y + x.z + x.w;
    #pragma unroll
    for (int off = 1; off < 64; off <<= 1) s += __shfl_xor(s, off, 64);
    float mean = s * (1.f/DD);
    float dx = x.x-mean, dy = x.y-mean, dz = x.z-mean, dw = x.w-mean;
    float v = dx*dx + dy*dy + dz*dz + dw*dw;
    #pragma unroll
    for (int off = 1; off < 64; off <<= 1) v += __shfl_xor(v, off, 64);
    float rstd = rsqrtf(v*(1.f/DD) + 1e-5f);
    float4 g4 = *(const float4*)&g[lane*4];
    float4 b4 = *(const float4*)&b[lane*4];
    float4 o;
    o.x = dx*rstd*g4.x + b4.x;
    o.y = dy*rstd*g4.y + b4.y;
    o.z = dz*rstd*g4.z + b4.z;
    o.w = dw*rstd*g4.w + b4.w;
    *(float4*)&c[(size_t)row*DD + lane*4] = o;
    ushort4 u;
    u.x = f2bf(o.x); u.y = f2bf(o.y); u.z = f2bf(o.z); u.w = f2bf(o.w);
    *(ushort4*)&cbf[(size_t)row*DD + lane*4] = u;
    if (ow != nullptr) {   // fused output head (target rows, local indexing)
        float4 wv = *(const float4*)&ow[lane*4];
        float ss = o.x*wv.x + o.y*wv.y + o.z*wv.z + o.w*wv.w;
        #pragma unroll
        for (int off = 1; off < 64; off <<= 1) ss += __shfl_xor(ss, off, 64);
        if (lane == 0) out[row] = expf(ss + ob[0]) * expo[row];
    }
}

extern "C" void kernel_launch(void* const* d_in, const int* in_sizes, int n_in,
                              void* d_out, int out_size, void* d_ws, size_t ws_size,
                              hipStream_t stream) {
    const float* c_ctx            = (const float*)d_in[0];
    const float* c_tgt            = (const float*)d_in[1];
    const float* y_context        = (const float*)d_in[2];
    const float* exposure_context = (const float*)d_in[3];
    const float* exposure_target  = (const float*)d_in[4];
    const float* dec_W1           = (const float*)d_in[5];
    const float* dec_b1           = (const float*)d_in[6];
    const float* dec_W2           = (const float*)d_in[7];
    const float* dec_b2           = (const float*)d_in[8];
    const float* log_kappa        = (const float*)d_in[9];
    const float* WQ               = (const float*)d_in[10];
    const float* bQ               = (const float*)d_in[11];
    const float* WK               = (const float*)d_in[12];
    const float* bK               = (const float*)d_in[13];
    const float* WV               = (const float*)d_in[14];
    const float* bV               = (const float*)d_in[15];
    const float* WO               = (const float*)d_in[16];
    const float* bO               = (const float*)d_in[17];
    const float* ln1_g            = (const float*)d_in[18];
    const float* ln1_b            = (const float*)d_in[19];
    const float* ln2_g            = (const float*)d_in[20];
    const float* ln2_b            = (const float*)d_in[21];
    const float* ffn_W1           = (const float*)d_in[22];
    const float* ffn_b1           = (const float*)d_in[23];
    const float* ffn_W2           = (const float*)d_in[24];
    const float* ffn_b2           = (const float*)d_in[25];
    const float* out_W            = (const float*)d_in[26];
    const float* out_b            = (const float*)d_in[27];
    float* out = (float*)d_out;

    float* ws = (float*)d_ws;
    float*  c    = ws;                          // 4096*256 f32
    float*  T    = ws + 1048576;                // 4096*256 f32 (also attn-L2 partial scratch)
    ushort* ub   = (ushort*)(ws + 2097152);
    ushort* c_bf = ub;                          // 4096*256 bf16
    ushort* Qh   = ub + 1048576;                // [8][4096][32] bf16, pre-scaled
    ushort* Khb  = ub + 2097152;                // [8][4096][32] bf16
    ushort* Vt   = ub + 3145728;                // [256][4096] bf16 (V transposed)
    ushort* AO   = ub + 4194304;                // 4096*256 bf16
    ushort* wbf  = ub + 5242880;                // 2*786432 bf16 weights + dec_W2t 65536
    ushort* wdec = wbf + 1572864;               // dec_W2t [256][256]
    float*  bqkv = (float*)(ub + 6881280);      // 2*768 f32
    ushort* tv   = AO;                          // 4096*256 bf16, dead after gemm5
    ushort* Hd   = Qh;                          // aliases Qh.. (dead then)
    float*  pml  = T;                           // [2][8][1024][2] f32 (32K floats)
    float*  pacc = T + 32768;                   // [2][8][1024][32] f32 (512K floats)

    convert_kernel<<<dim3(4355, 2), 256, 0, stream>>>(WQ, WK, WV, WO, ffn_W1, ffn_W2,
                                                      bQ, bK, bV, dec_W2,
                                                      y_context, dec_W1, dec_b1, tv,
                                                      wbf, bqkv);
    gemm_bf<<<dim3(4, 64), 256, 0, stream>>>(tv, wdec, dec_b2, c, c_bf, NTOK, DD, DD, 5,
                                             exposure_context, c_ctx, c_tgt, log_kappa);
    // ---- layer 0 (full 4096 rows) ----
    {
        ushort* wl = wbf;
        gemm_bf<<<dim3(12, 64), 256, 0, stream>>>(c_bf, wl, bqkv, Qh, Vt, NTOK, 768, DD, 4,
                                                  nullptr, nullptr, nullptr, nullptr);
        attn_kernel<<<dim3(64, NH, 1), 1024, 0, stream>>>(Qh, Khb, Vt, AO, nullptr, nullptr, 0);
        gemm_bf<<<dim3(4, 64),  256, 0, stream>>>(AO, wl + 196608, bO, T, nullptr, NTOK, DD, DD, 0,
                                                  nullptr, nullptr, nullptr, nullptr);
        ln_kernel<<<NTOK/4, 256, 0, stream>>>(c, T, ln1_g, ln1_b, c_bf,
                                              nullptr, nullptr, nullptr, nullptr);
        gemm_bf<<<dim3(16, 64), 256, 0, stream>>>(c_bf, wl + 262144, ffn_b1, Hd, nullptr, NTOK, FFD, DD, 3,
                                                  nullptr, nullptr, nullptr, nullptr);
        gemm_bf<<<dim3(4, 64),  256, 0, stream>>>(Hd, wl + 524288, ffn_b2, T, nullptr, NTOK, DD, FFD, 0,
                                                  nullptr, nullptr, nullptr, nullptr);
        ln_kernel<<<NTOK/4, 256, 0, stream>>>(c, T, ln2_g, ln2_b, c_bf,
                                              nullptr, nullptr, nullptr, nullptr);
    }
    // ---- layer 1 (target rows only after QKV; output depends only on c[NC:]) ----
    {
        ushort* wl = wbf + 786432;
        gemm_bf<<<dim3(12, 64), 256, 0, stream>>>(c_bf, wl, bqkv + 768, Qh, Vt, NTOK, 768, DD, 4,
                                                  nullptr, nullptr, nullptr, nullptr);
        attn_kernel<<<dim3(16, NH, 2), 1024, 0, stream>>>(Qh, Khb, Vt, AO, pml, pacc, 1);
        combine_kernel<<<1024, 256, 0, stream>>>(pml, pacc, AO);
        gemm_bf<<<dim3(4, 16),  256, 0, stream>>>(AO + (size_t)NC_*DD, wl + 196608, bO + DD, T, nullptr,
                                                  NT_, DD, DD, 0, nullptr, nullptr, nullptr, nullptr);
        ln_kernel<<<NT_/4, 256, 0, stream>>>(c + (size_t)NC_*DD, T, ln1_g + DD, ln1_b + DD,
                                             c_bf + (size_t)NC_*DD,
                                             nullptr, nullptr, nullptr, nullptr);
        gemm_bf<<<dim3(16, 16), 256, 0, stream>>>(c_bf + (size_t)NC_*DD, wl + 262144, ffn_b1 + FFD,
                                                  Hd, nullptr, NT_, FFD, DD, 3,
                                                  nullptr, nullptr, nullptr, nullptr);
        gemm_bf<<<dim3(4, 16),  256, 0, stream>>>(Hd, wl + 524288, ffn_b2 + DD, T, nullptr,
                                                  NT_, DD, FFD, 0, nullptr, nullptr, nullptr, nullptr);
        ln_kernel<<<NT_/4, 256, 0, stream>>>(c + (size_t)NC_*DD, T, ln2_g + DD, ln2_b + DD,
                                             c_bf + (size_t)NC_*DD,
                                             out_W, out_b, exposure_target, out);
    }
}

// Round 12
// 143.595 us; speedup vs baseline: 1.3818x; 1.0657x over previous
//
#include <hip/hip_runtime.h>
#include <hip/hip_bf16.h>
#include <math.h>

#define NC_   3072
#define NT_   1024
#define NTOK  4096
#define DD    256
#define NH    8
#define HDIM  32
#define NL    2
#define FFD   1024

typedef __attribute__((ext_vector_type(8))) short short8;
typedef __attribute__((ext_vector_type(4))) float f32x4;

#if __has_builtin(__builtin_amdgcn_exp2f)
#define EXP2(x) __builtin_amdgcn_exp2f(x)
#else
#define EXP2(x) exp2f(x)
#endif

#define QSCALE 0.25503482964f   // log2(e)/sqrt(32), folded into Q at GEMM epilogue

__device__ inline float bf2f(ushort u) { return __uint_as_float(((unsigned)u) << 16); }
__device__ inline ushort f2bf(float x) {
    __hip_bfloat16 h = __float2bfloat16(x);
    return *reinterpret_cast<ushort*>(&h);
}
__device__ inline void gload16(const void* g, void* l) {
    __builtin_amdgcn_global_load_lds(
        (const __attribute__((address_space(1))) void*)g,
        (__attribute__((address_space(3))) void*)l, 16, 0, 0);
}

// ---------------- weight convert + tanh stage (fused) ----------------
__global__ __launch_bounds__(256) void convert_kernel(
    const float* __restrict__ WQ, const float* __restrict__ WK,
    const float* __restrict__ WV, const float* __restrict__ WO,
    const float* __restrict__ W1, const float* __restrict__ W2,
    const float* __restrict__ bQ, const float* __restrict__ bK,
    const float* __restrict__ bV, const float* __restrict__ dW2,
    const float* __restrict__ y_context, const float* __restrict__ dec_W1,
    const float* __restrict__ dec_b1, ushort* __restrict__ tv,
    ushort* __restrict__ wbf, float* __restrict__ bqkv)
{
    int l = blockIdx.y;
    int idx = blockIdx.x * 256 + threadIdx.x;
    if (idx >= 852736) {                // tanh region (l==0 only)
        if (l != 0) return;
        int i2 = idx - 852736;          // 0..262143
        int m = i2 >> 6, k = (i2 & 63) * 4;
        float y = (m < NC_) ? y_context[m] : 0.f;
        ushort4 u;
        u.x = f2bf(tanhf(y * dec_W1[k+0] + dec_b1[k+0]));
        u.y = f2bf(tanhf(y * dec_W1[k+1] + dec_b1[k+1]));
        u.z = f2bf(tanhf(y * dec_W1[k+2] + dec_b1[k+2]));
        u.w = f2bf(tanhf(y * dec_W1[k+3] + dec_b1[k+3]));
        *(ushort4*)&tv[(size_t)i2 * 4] = u;
        return;
    }
    if (idx >= 787200) {                // shared dec_W2t (l==0 only)
        if (l != 0) return;
        int i = idx - 787200;           // 0..65535
        int n = i >> 8, k = i & 255;
        wbf[(size_t)2*786432 + i] = f2bf(dW2[(size_t)k*256 + n]);
        return;
    }
    if (idx >= 786432) {
        int i = idx - 786432;           // < 768
        float bv = (i < 256) ? bQ[l*256 + i]
                 : (i < 512) ? bK[l*256 + (i - 256)]
                             : bV[l*256 + (i - 512)];
        bqkv[l*768 + i] = bv;
        return;
    }
    float v;
    if (idx < 196608) {                 // WQKVt[768][256]
        int n = idx >> 8, k = idx & 255;
        v = (n < 256) ? WQ[(size_t)(l*256 + k)*256 + n]
          : (n < 512) ? WK[(size_t)(l*256 + k)*256 + (n-256)]
                      : WV[(size_t)(l*256 + k)*256 + (n-512)];
    } else if (idx < 262144) {          // WOt[256][256]
        int i = idx - 196608, n = i >> 8, k = i & 255;
        v = WO[(size_t)(l*256 + k)*256 + n];
    } else if (idx < 524288) {          // W1t[1024][256]
        int i = idx - 262144, n = i >> 8, k = i & 255;
        v = W1[(size_t)(l*256 + k)*1024 + n];
    } else {                            // W2t[256][1024]
        int i = idx - 524288, n = i >> 10, k = i & 1023;
        v = W2[(size_t)(l*1024 + k)*256 + n];
    }
    wbf[(size_t)l*786432 + idx] = f2bf(v);
}

// ---------------- bf16 MFMA GEMM 64x64 (4 waves) ----------------
// mode: 0=f32, 3=bf16+relu, 4=QKV split, 5=decorator
__global__ __launch_bounds__(256) void gemm_bf(
    const ushort* __restrict__ A, const ushort* __restrict__ Bt,
    const float* __restrict__ bias, void* __restrict__ Cv, void* __restrict__ Cv2,
    int M, int N, int K, int mode,
    const float* __restrict__ xc, const float* __restrict__ ca,
    const float* __restrict__ cb, const float* __restrict__ lk)
{
    __shared__ ushort As[64*64];   // [64 m][64 k], XOR-swizzled: byte ^= (row&7)<<4
    __shared__ ushort Bs[64*64];
    int tid = threadIdx.x, lane = tid & 63, w = tid >> 6;
    int wm = w >> 1, wn = w & 1;
    int m0 = blockIdx.y * 64, n0 = blockIdx.x * 64;
    int col = lane & 15, grp = lane >> 4;
    f32x4 acc[2][2] = {};

    for (int k0 = 0; k0 < K; k0 += 64) {
        __syncthreads();
        #pragma unroll
        for (int s = 0; s < 2; ++s) {
            int i = tid + s*256;
            int r = i >> 3, j = i & 7;
            int kb = (j*16) ^ ((r & 7) << 4);    // pre-swizzled source byte offset
            gload16((const char*)(A  + (size_t)(m0 + r)*K + k0) + kb,
                    (char*)As + s*4096 + w*1024);
            gload16((const char*)(Bt + (size_t)(n0 + r)*K + k0) + kb,
                    (char*)Bs + s*4096 + w*1024);
        }
        __syncthreads();
        #pragma unroll
        for (int kk = 0; kk < 64; kk += 32) {
            short8 a[2], b[2];
            #pragma unroll
            for (int f = 0; f < 2; ++f) {
                int ra = wm*32 + f*16 + col;
                a[f] = *(const short8*)((char*)As + ra*128 + (((kk + grp*8)*2) ^ ((ra & 7) << 4)));
                int rb = wn*32 + f*16 + col;
                b[f] = *(const short8*)((char*)Bs + rb*128 + (((kk + grp*8)*2) ^ ((rb & 7) << 4)));
            }
            #pragma unroll
            for (int fm = 0; fm < 2; ++fm)
                #pragma unroll
                for (int fn = 0; fn < 2; ++fn)
                    acc[fm][fn] = __builtin_amdgcn_mfma_f32_16x16x32_bf16(a[fm], b[fn], acc[fm][fn], 0, 0, 0);
        }
    }
    float kap = (mode == 5) ? log1pf(expf(lk[0])) : 0.f;
    #pragma unroll
    for (int fm = 0; fm < 2; ++fm) {
        #pragma unroll
        for (int fn = 0; fn < 2; ++fn) {
            int ncol = n0 + wn*32 + fn*16 + col;
            int mbase = m0 + wm*32 + fm*16 + grp*4;
            float bs = bias[ncol];
            if (mode == 4 && ncol >= 512) {          // Vt transposed
                ushort* base = (ushort*)Cv2 - (size_t)512*M;
                ushort4 u;
                u.x = f2bf(acc[fm][fn][0] + bs); u.y = f2bf(acc[fm][fn][1] + bs);
                u.z = f2bf(acc[fm][fn][2] + bs); u.w = f2bf(acc[fm][fn][3] + bs);
                *(ushort4*)(base + (size_t)ncol*M + mbase) = u;
            } else if (mode == 4) {                  // Q (scaled) / K head-major
                int cc = ncol & 255, hh = cc >> 5, hd = cc & 31;
                ushort* base = (ushort*)Cv + ((ncol < 256) ? 0u : 1048576u);
                float sc = (ncol < 256) ? QSCALE : 1.f;
                #pragma unroll
                for (int r = 0; r < 4; ++r)
                    base[((size_t)hh*M + mbase + r)*HDIM + hd] = f2bf((acc[fm][fn][r] + bs) * sc);
            } else if (mode == 5) {                  // decorator epilogue
                #pragma unroll
                for (int r = 0; r < 4; ++r) {
                    int m = mbase + r;
                    float basev = (m < NC_) ? ca[(size_t)m*DD + ncol]
                                            : cb[(size_t)(m - NC_)*DD + ncol];
                    float wv = 0.f;
                    if (m < NC_) { float e = xc[m]; wv = e / (e + kap); }
                    float v = basev + wv * (acc[fm][fn][r] + bs);
                    ((float*)Cv)[(size_t)m*DD + ncol] = v;
                    ((ushort*)Cv2)[(size_t)m*DD + ncol] = f2bf(v);
                }
            } else {
                #pragma unroll
                for (int r = 0; r < 4; ++r) {
                    float v = acc[fm][fn][r] + bs;
                    if (mode == 3) v = fmaxf(v, 0.f);
                    if (mode == 0) ((float*)Cv)[(size_t)(mbase + r)*N + ncol] = v;
                    else           ((ushort*)Cv)[(size_t)(mbase + r)*N + ncol] = f2bf(v);
                }
            }
        }
    }
}

// ---------------- flash attention: 16 waves, 64 q/block, 128-key tiles ----------------
// No-max softmax (scores bounded: p = exp2(s) directly; f32/bf16 exponent range makes
// overflow impossible below s~120). K/V staged via global_load_lds (1 inst/wave/tile):
// linear LDS dest + inverse-permuted XOR-swizzled per-lane SOURCE + swizzled reads
// (rule #21 both-sides). K: 64 lines x 128B (2 keys/line, slot ^= L&7, conflict-free);
// V: 32 rows x 256B (slot ^= d&7, 2-way). P stays in registers (QK^T D-layout == PV
// B-frag via key permutation). lsum via ones-MFMA. l2mode as R11 (partials, no max).
__global__ __launch_bounds__(1024, 8) void attn_kernel(
    const ushort* __restrict__ Qh, const ushort* __restrict__ Kh,
    const ushort* __restrict__ Vt, ushort* __restrict__ AO,
    float* __restrict__ pml, float* __restrict__ pacc, int l2mode)
{
    __shared__ __align__(16) char smem[37888];   // K0@0 K1@8192 V0@16384 V1@24576; cacc overlay
    __shared__ float cml[16][16];
    int tid = threadIdx.x;
    int w = tid >> 6, lane = tid & 63;
    int q = lane & 15, g = lane >> 4;
    int wq = w & 3, kh = w >> 2;
    int h = blockIdx.y;
    int zb = blockIdx.z;
    int q0   = l2mode ? (NC_ + blockIdx.x * 64) : (blockIdx.x * 64);
    int kbeg = l2mode ? zb * 1536 : 0;
    int do_self = l2mode ? (zb == 0) : (q0 >= NC_);
    int nt = l2mode ? 12 : (((q0 >= NC_) ? NC_ : NTOK) >> 7);

    // Q B-frag (pre-scaled, head-major)
    short8 bq = *(const short8*)&Qh[((size_t)h*NTOK + q0 + wq*16 + q)*HDIM + g*8];
    short8 ones;
    #pragma unroll
    for (int e = 0; e < 8; ++e) ones[e] = (short)0x3F80;   // bf16(1.0)

    f32x4 acc0 = {0.f,0.f,0.f,0.f}, acc1 = {0.f,0.f,0.f,0.f};
    f32x4 accl = {0.f,0.f,0.f,0.f};
    const f32x4 z = {0.f,0.f,0.f,0.f};

    // ---- staging source (per-lane, inverse-permuted + pre-swizzled) ----
    const ushort* src0;
    char *dst0, *dst1;
    size_t sstep;
    if (w < 8) {        // K: wave w stages lines w*8..w*8+7 (1KB)
        int L  = (w << 3) + (lane >> 3);
        int s  = lane & 7;
        int e  = s ^ (L & 7);
        int r  = 2*L + (e >> 2);         // physical key-row 0..127
        int qt = e & 3;
        int ch = r >> 5, rr = r & 31;
        int hi = (rr >> 4) & 1, qp = rr & 15;
        int key = ch*32 + (((qp >> 2) << 3) | (hi << 2) | (qp & 3));   // inverse perm
        src0 = Kh + ((size_t)h*NTOK + kbeg + key)*HDIM + qt*8;
        sstep = (size_t)128*HDIM;
        dst0 = smem + w*1024;
        dst1 = dst0 + 8192;
    } else {            // V: wave u stages rows u*4..u*4+3 (1KB)
        int u = w - 8;
        int d = u*4 + (lane >> 4);
        int s = lane & 15;
        int e = (s & 8) | ((s ^ (d & 7)) & 7);
        src0 = Vt + ((size_t)(h*HDIM + d))*NTOK + kbeg + e*8;
        sstep = 128;
        dst0 = smem + 16384 + u*1024;
        dst1 = dst0 + 8192;
    }
    gload16(src0, dst0);                 // tile 0
    asm volatile("s_waitcnt vmcnt(0)" ::: "memory");
    __builtin_amdgcn_s_barrier();
    __builtin_amdgcn_sched_barrier(0);

    // ---- compute read pointers (swizzled) ----
    const int L0 = kh*16 + (q >> 1);
    const char* kb0 = smem + L0*128 + (((((q & 1) << 2) + g) ^ (L0 & 7)) << 4);
    const int vslot = (kh << 2) + g;
    const int vsx = (vslot & 8) | ((vslot ^ (q & 7)) & 7);
    const char* vb0 = smem + 16384 + q*256 + (vsx << 4);
    const char* vb1 = vb0 + 16*256;

    for (int t = 0; t < nt; ++t) {
        int cur = t & 1;
        if (t + 1 < nt)
            gload16(src0 + (size_t)(t+1)*sstep, cur ? dst0 : dst1);
        const char* kb = kb0 + cur*8192;
        short8 ka0 = *(const short8*)(kb);
        short8 ka1 = *(const short8*)(kb + 1024);
        __builtin_amdgcn_s_setprio(1);
        f32x4 st0 = __builtin_amdgcn_mfma_f32_16x16x32_bf16(ka0, bq, z, 0, 0, 0);
        f32x4 st1 = __builtin_amdgcn_mfma_f32_16x16x32_bf16(ka1, bq, z, 0, 0, 0);
        __builtin_amdgcn_s_setprio(0);
        float p0 = EXP2(st0[0]), p1 = EXP2(st0[1]);
        float p2 = EXP2(st0[2]), p3 = EXP2(st0[3]);
        float p4 = EXP2(st1[0]), p5 = EXP2(st1[1]);
        float p6 = EXP2(st1[2]), p7 = EXP2(st1[3]);
        short8 pf;
        pf[0] = (short)f2bf(p0); pf[1] = (short)f2bf(p1);
        pf[2] = (short)f2bf(p2); pf[3] = (short)f2bf(p3);
        pf[4] = (short)f2bf(p4); pf[5] = (short)f2bf(p5);
        pf[6] = (short)f2bf(p6); pf[7] = (short)f2bf(p7);
        short8 va0 = *(const short8*)(vb0 + cur*8192);
        short8 va1 = *(const short8*)(vb1 + cur*8192);
        __builtin_amdgcn_s_setprio(1);
        acc0 = __builtin_amdgcn_mfma_f32_16x16x32_bf16(va0, pf, acc0, 0, 0, 0);
        acc1 = __builtin_amdgcn_mfma_f32_16x16x32_bf16(va1, pf, acc1, 0, 0, 0);
        accl = __builtin_amdgcn_mfma_f32_16x16x32_bf16(ones, pf, accl, 0, 0, 0);
        __builtin_amdgcn_s_setprio(0);
        if (t + 1 < nt) {
            asm volatile("s_waitcnt vmcnt(0)" ::: "memory");
            __builtin_amdgcn_s_barrier();
            __builtin_amdgcn_sched_barrier(0);
        }
    }

    float lsum = accl[0];   // full sum over this wave's keys (cross-group via MFMA)

    if (do_self && kh == 0) {   // self-key (structural mask), once per query
        int qg = q0 + wq*16 + q;
        short8 kv = *(const short8*)&Kh[((size_t)h*NTOK + qg)*HDIM + g*8];
        float d8 = 0.f;
        #pragma unroll
        for (int e = 0; e < 8; ++e) d8 += bf2f((ushort)bq[e]) * bf2f((ushort)kv[e]);
        d8 += __shfl_xor(d8, 16, 64);
        d8 += __shfl_xor(d8, 32, 64);    // already log2-scaled (Q pre-scaled)
        float pp = EXP2(d8);
        lsum += pp;
        #pragma unroll
        for (int r = 0; r < 4; ++r) {
            acc0[r] += pp * bf2f(Vt[(size_t)(h*HDIM + g*4 + r)*NTOK + qg]);
            acc1[r] += pp * bf2f(Vt[(size_t)(h*HDIM + 16 + g*4 + r)*NTOK + qg]);
        }
    }

    __syncthreads();                      // K/V tiles dead; reuse smem as combine buffer
    float* cacc = (float*)smem;           // [16][32][17]
    #pragma unroll
    for (int r = 0; r < 4; ++r) {
        cacc[(w*32 + g*4 + r)*17 + q]      = acc0[r];
        cacc[(w*32 + 16 + g*4 + r)*17 + q] = acc1[r];
    }
    if (g == 0) cml[w][q] = lsum;
    __syncthreads();

    if (w < 4) {   // merge over key-quarters {w, w+4, w+8, w+12}; q-group w (plain sums)
        float L = cml[w][q] + cml[w+4][q] + cml[w+8][q] + cml[w+12][q];
        if (!l2mode) {
            float inv = 1.f / L;
            ushort* dst = AO + (size_t)(q0 + w*16 + q)*DD + h*HDIM;
            ushort4 o0, o1;
            #pragma unroll
            for (int r = 0; r < 4; ++r) {
                int e0 = g*4 + r, e1 = 16 + g*4 + r;
                float O0 = cacc[(w*32+e0)*17+q] + cacc[((w+4)*32+e0)*17+q]
                         + cacc[((w+8)*32+e0)*17+q] + cacc[((w+12)*32+e0)*17+q];
                float O1 = cacc[(w*32+e1)*17+q] + cacc[((w+4)*32+e1)*17+q]
                         + cacc[((w+8)*32+e1)*17+q] + cacc[((w+12)*32+e1)*17+q];
                ((ushort*)&o0)[r] = f2bf(O0 * inv);
                ((ushort*)&o1)[r] = f2bf(O1 * inv);
            }
            *(ushort4*)(dst + g*4) = o0;
            *(ushort4*)(dst + 16 + g*4) = o1;
        } else {     // partial out: unnormalized O + l
            int qi = q0 - NC_ + w*16 + q;
            float* pa = pacc + (((size_t)zb*NH + h)*NT_ + qi)*32;
            #pragma unroll
            for (int r = 0; r < 4; ++r) {
                int e0 = g*4 + r, e1 = 16 + g*4 + r;
                pa[e0] = cacc[(w*32+e0)*17+q] + cacc[((w+4)*32+e0)*17+q]
                       + cacc[((w+8)*32+e0)*17+q] + cacc[((w+12)*32+e0)*17+q];
                pa[e1] = cacc[(w*32+e1)*17+q] + cacc[((w+4)*32+e1)*17+q]
                       + cacc[((w+8)*32+e1)*17+q] + cacc[((w+12)*32+e1)*17+q];
            }
            if (g == 0) pml[((size_t)zb*NH + h)*NT_ + qi] = L;
        }
    }
}

// ---------------- combine: merge of layer-2 attn partials -> AO (plain sums) ----------------
__global__ __launch_bounds__(256) void combine_kernel(
    const float* __restrict__ pml, const float* __restrict__ pacc, ushort* __restrict__ AO)
{
    int item = blockIdx.x * 8 + (threadIdx.x >> 5);   // 8192 items = 8 h x 1024 q
    int d = threadIdx.x & 31;
    int hh = item >> 10, qi = item & 1023;
    size_t i0 = ((size_t)0*NH + hh)*NT_ + qi;
    size_t i1 = ((size_t)1*NH + hh)*NT_ + qi;
    float inv = 1.f / (pml[i0] + pml[i1]);
    float O = pacc[i0*32 + d] + pacc[i1*32 + d];
    AO[(size_t)(NC_ + qi)*DD + hh*HDIM + d] = f2bf(O * inv);
}

// ---------------- layernorm: c = LN(c + delta)*g + b ; + bf16 copy; optional head ----
__global__ __launch_bounds__(256) void ln_kernel(
    float* __restrict__ c, const float* __restrict__ delta,
    const float* __restrict__ g, const float* __restrict__ b, ushort* __restrict__ cbf,
    const float* __restrict__ ow, const float* __restrict__ ob,
    const float* __restrict__ expo, float* __restrict__ out)
{
    int tid = threadIdx.x;
    int wid = tid >> 6, lane = tid & 63;
    int row = blockIdx.x * 4 + wid;
    float4 x  = *(const float4*)&c[(size_t)row*DD + lane*4];
    float4 dl = *(const float4*)&delta[(size_t)row*DD + lane*4];
    x.x += dl.x; x.y += dl.y; x.z += dl.z; x.w += dl.w;
    float s = x.x + x.y + x.z + x.w;
    #pragma unroll
    for (int off = 1; off < 64; off <<= 1) s += __shfl_xor(s, off, 64);
    float mean = s * (1.f/DD);
    float dx = x.x-mean, dy = x.y-mean, dz = x.z-mean, dw = x.w-mean;
    float v = dx*dx + dy*dy + dz*dz + dw*dw;
    #pragma unroll
    for (int off = 1; off < 64; off <<= 1) v += __shfl_xor(v, off, 64);
    float rstd = rsqrtf(v*(1.f/DD) + 1e-5f);
    float4 g4 = *(const float4*)&g[lane*4];
    float4 b4 = *(const float4*)&b[lane*4];
    float4 o;
    o.x = dx*rstd*g4.x + b4.x;
    o.y = dy*rstd*g4.y + b4.y;
    o.z = dz*rstd*g4.z + b4.z;
    o.w = dw*rstd*g4.w + b4.w;
    *(float4*)&c[(size_t)row*DD + lane*4] = o;
    ushort4 u;
    u.x = f2bf(o.x); u.y = f2bf(o.y); u.z = f2bf(o.z); u.w = f2bf(o.w);
    *(ushort4*)&cbf[(size_t)row*DD + lane*4] = u;
    if (ow != nullptr) {   // fused output head (target rows, local indexing)
        float4 wv = *(const float4*)&ow[lane*4];
        float ss = o.x*wv.x + o.y*wv.y + o.z*wv.z + o.w*wv.w;
        #pragma unroll
        for (int off = 1; off < 64; off <<= 1) ss += __shfl_xor(ss, off, 64);
        if (lane == 0) out[row] = expf(ss + ob[0]) * expo[row];
    }
}

extern "C" void kernel_launch(void* const* d_in, const int* in_sizes, int n_in,
                              void* d_out, int out_size, void* d_ws, size_t ws_size,
                              hipStream_t stream) {
    const float* c_ctx            = (const float*)d_in[0];
    const float* c_tgt            = (const float*)d_in[1];
    const float* y_context        = (const float*)d_in[2];
    const float* exposure_context = (const float*)d_in[3];
    const float* exposure_target  = (const float*)d_in[4];
    const float* dec_W1           = (const float*)d_in[5];
    const float* dec_b1           = (const float*)d_in[6];
    const float* dec_W2           = (const float*)d_in[7];
    const float* dec_b2           = (const float*)d_in[8];
    const float* log_kappa        = (const float*)d_in[9];
    const float* WQ               = (const float*)d_in[10];
    const float* bQ               = (const float*)d_in[11];
    const float* WK               = (const float*)d_in[12];
    const float* bK               = (const float*)d_in[13];
    const float* WV               = (const float*)d_in[14];
    const float* bV               = (const float*)d_in[15];
    const float* WO               = (const float*)d_in[16];
    const float* bO               = (const float*)d_in[17];
    const float* ln1_g            = (const float*)d_in[18];
    const float* ln1_b            = (const float*)d_in[19];
    const float* ln2_g            = (const float*)d_in[20];
    const float* ln2_b            = (const float*)d_in[21];
    const float* ffn_W1           = (const float*)d_in[22];
    const float* ffn_b1           = (const float*)d_in[23];
    const float* ffn_W2           = (const float*)d_in[24];
    const float* ffn_b2           = (const float*)d_in[25];
    const float* out_W            = (const float*)d_in[26];
    const float* out_b            = (const float*)d_in[27];
    float* out = (float*)d_out;

    float* ws = (float*)d_ws;
    float*  c    = ws;                          // 4096*256 f32
    float*  T    = ws + 1048576;                // 4096*256 f32 (also attn-L2 partial scratch)
    ushort* ub   = (ushort*)(ws + 2097152);
    ushort* c_bf = ub;                          // 4096*256 bf16
    ushort* Qh   = ub + 1048576;                // [8][4096][32] bf16, pre-scaled
    ushort* Khb  = ub + 2097152;                // [8][4096][32] bf16
    ushort* Vt   = ub + 3145728;                // [256][4096] bf16 (V transposed)
    ushort* AO   = ub + 4194304;                // 4096*256 bf16
    ushort* wbf  = ub + 5242880;                // 2*786432 bf16 weights + dec_W2t 65536
    ushort* wdec = wbf + 1572864;               // dec_W2t [256][256]
    float*  bqkv = (float*)(ub + 6881280);      // 2*768 f32
    ushort* tv   = AO;                          // 4096*256 bf16, dead after gemm5
    ushort* Hd   = Qh;                          // aliases Qh.. (dead then)
    float*  pml  = T;                           // [2][8][1024] f32
    float*  pacc = T + 16384;                   // [2][8][1024][32] f32

    convert_kernel<<<dim3(4355, 2), 256, 0, stream>>>(WQ, WK, WV, WO, ffn_W1, ffn_W2,
                                                      bQ, bK, bV, dec_W2,
                                                      y_context, dec_W1, dec_b1, tv,
                                                      wbf, bqkv);
    gemm_bf<<<dim3(4, 64), 256, 0, stream>>>(tv, wdec, dec_b2, c, c_bf, NTOK, DD, DD, 5,
                                             exposure_context, c_ctx, c_tgt, log_kappa);
    // ---- layer 0 (full 4096 rows) ----
    {
        ushort* wl = wbf;
        gemm_bf<<<dim3(12, 64), 256, 0, stream>>>(c_bf, wl, bqkv, Qh, Vt, NTOK, 768, DD, 4,
                                                  nullptr, nullptr, nullptr, nullptr);
        attn_kernel<<<dim3(64, NH, 1), 1024, 0, stream>>>(Qh, Khb, Vt, AO, nullptr, nullptr, 0);
        gemm_bf<<<dim3(4, 64),  256, 0, stream>>>(AO, wl + 196608, bO, T, nullptr, NTOK, DD, DD, 0,
                                                  nullptr, nullptr, nullptr, nullptr);
        ln_kernel<<<NTOK/4, 256, 0, stream>>>(c, T, ln1_g, ln1_b, c_bf,
                                              nullptr, nullptr, nullptr, nullptr);
        gemm_bf<<<dim3(16, 64), 256, 0, stream>>>(c_bf, wl + 262144, ffn_b1, Hd, nullptr, NTOK, FFD, DD, 3,
                                                  nullptr, nullptr, nullptr, nullptr);
        gemm_bf<<<dim3(4, 64),  256, 0, stream>>>(Hd, wl + 524288, ffn_b2, T, nullptr, NTOK, DD, FFD, 0,
                                                  nullptr, nullptr, nullptr, nullptr);
        ln_kernel<<<NTOK/4, 256, 0, stream>>>(c, T, ln2_g, ln2_b, c_bf,
                                              nullptr, nullptr, nullptr, nullptr);
    }
    // ---- layer 1 (target rows only after QKV) ----
    {
        ushort* wl = wbf + 786432;
        gemm_bf<<<dim3(12, 64), 256, 0, stream>>>(c_bf, wl, bqkv + 768, Qh, Vt, NTOK, 768, DD, 4,
                                                  nullptr, nullptr, nullptr, nullptr);
        attn_kernel<<<dim3(16, NH, 2), 1024, 0, stream>>>(Qh, Khb, Vt, AO, pml, pacc, 1);
        combine_kernel<<<1024, 256, 0, stream>>>(pml, pacc, AO);
        gemm_bf<<<dim3(4, 16),  256, 0, stream>>>(AO + (size_t)NC_*DD, wl + 196608, bO + DD, T, nullptr,
                                                  NT_, DD, DD, 0, nullptr, nullptr, nullptr, nullptr);
        ln_kernel<<<NT_/4, 256, 0, stream>>>(c + (size_t)NC_*DD, T, ln1_g + DD, ln1_b + DD,
                                             c_bf + (size_t)NC_*DD,
                                             nullptr, nullptr, nullptr, nullptr);
        gemm_bf<<<dim3(16, 16), 256, 0, stream>>>(c_bf + (size_t)NC_*DD, wl + 262144, ffn_b1 + FFD,
                                                  Hd, nullptr, NT_, FFD, DD, 3,
                                                  nullptr, nullptr, nullptr, nullptr);
        gemm_bf<<<dim3(4, 16),  256, 0, stream>>>(Hd, wl + 524288, ffn_b2 + DD, T, nullptr,
                                                  NT_, DD, FFD, 0, nullptr, nullptr, nullptr, nullptr);
        ln_kernel<<<NT_/4, 256, 0, stream>>>(c + (size_t)NC_*DD, T, ln2_g + DD, ln2_b + DD,
                                             c_bf + (size_t)NC_*DD,
                                             out_W, out_b, exposure_target, out);
    }
}

// Round 13
// 142.436 us; speedup vs baseline: 1.3931x; 1.0081x over previous
//
#include <hip/hip_runtime.h>
#include <hip/hip_bf16.h>
#include <math.h>

#define NC_   3072
#define NT_   1024
#define NTOK  4096
#define DD    256
#define NH    8
#define HDIM  32
#define NL    2
#define FFD   1024

typedef __attribute__((ext_vector_type(8))) short short8;
typedef __attribute__((ext_vector_type(4))) float f32x4;

#if __has_builtin(__builtin_amdgcn_exp2f)
#define EXP2(x) __builtin_amdgcn_exp2f(x)
#else
#define EXP2(x) exp2f(x)
#endif

#define QSCALE 0.25503482964f   // log2(e)/sqrt(32), folded into Q at GEMM epilogue

__device__ inline float bf2f(ushort u) { return __uint_as_float(((unsigned)u) << 16); }
__device__ inline ushort f2bf(float x) {
    __hip_bfloat16 h = __float2bfloat16(x);
    return *reinterpret_cast<ushort*>(&h);
}
__device__ inline void gload16(const void* g, void* l) {
    __builtin_amdgcn_global_load_lds(
        (const __attribute__((address_space(1))) void*)g,
        (__attribute__((address_space(3))) void*)l, 16, 0, 0);
}

// ---------------- weight convert + tanh stage (fused) ----------------
__global__ __launch_bounds__(256) void convert_kernel(
    const float* __restrict__ WQ, const float* __restrict__ WK,
    const float* __restrict__ WV, const float* __restrict__ WO,
    const float* __restrict__ W1, const float* __restrict__ W2,
    const float* __restrict__ bQ, const float* __restrict__ bK,
    const float* __restrict__ bV, const float* __restrict__ dW2,
    const float* __restrict__ y_context, const float* __restrict__ dec_W1,
    const float* __restrict__ dec_b1, ushort* __restrict__ tv,
    ushort* __restrict__ wbf, float* __restrict__ bqkv)
{
    int l = blockIdx.y;
    int idx = blockIdx.x * 256 + threadIdx.x;
    if (idx >= 852736) {                // tanh region (l==0 only)
        if (l != 0) return;
        int i2 = idx - 852736;          // 0..262143
        int m = i2 >> 6, k = (i2 & 63) * 4;
        float y = (m < NC_) ? y_context[m] : 0.f;
        ushort4 u;
        u.x = f2bf(tanhf(y * dec_W1[k+0] + dec_b1[k+0]));
        u.y = f2bf(tanhf(y * dec_W1[k+1] + dec_b1[k+1]));
        u.z = f2bf(tanhf(y * dec_W1[k+2] + dec_b1[k+2]));
        u.w = f2bf(tanhf(y * dec_W1[k+3] + dec_b1[k+3]));
        *(ushort4*)&tv[(size_t)i2 * 4] = u;
        return;
    }
    if (idx >= 787200) {                // shared dec_W2t (l==0 only)
        if (l != 0) return;
        int i = idx - 787200;           // 0..65535
        int n = i >> 8, k = i & 255;
        wbf[(size_t)2*786432 + i] = f2bf(dW2[(size_t)k*256 + n]);
        return;
    }
    if (idx >= 786432) {
        int i = idx - 786432;           // < 768
        float bv = (i < 256) ? bQ[l*256 + i]
                 : (i < 512) ? bK[l*256 + (i - 256)]
                             : bV[l*256 + (i - 512)];
        bqkv[l*768 + i] = bv;
        return;
    }
    float v;
    if (idx < 196608) {                 // WQKVt[768][256]
        int n = idx >> 8, k = idx & 255;
        v = (n < 256) ? WQ[(size_t)(l*256 + k)*256 + n]
          : (n < 512) ? WK[(size_t)(l*256 + k)*256 + (n-256)]
                      : WV[(size_t)(l*256 + k)*256 + (n-512)];
    } else if (idx < 262144) {          // WOt[256][256]
        int i = idx - 196608, n = i >> 8, k = i & 255;
        v = WO[(size_t)(l*256 + k)*256 + n];
    } else if (idx < 524288) {          // W1t[1024][256]
        int i = idx - 262144, n = i >> 8, k = i & 255;
        v = W1[(size_t)(l*256 + k)*1024 + n];
    } else {                            // W2t[256][1024]
        int i = idx - 524288, n = i >> 10, k = i & 1023;
        v = W2[(size_t)(l*1024 + k)*256 + n];
    }
    wbf[(size_t)l*786432 + idx] = f2bf(v);
}

// ---------------- bf16 MFMA GEMM 64x64 (4 waves) ----------------
// mode: 0=f32, 3=bf16+relu, 4=QKV split, 5=decorator
__global__ __launch_bounds__(256) void gemm_bf(
    const ushort* __restrict__ A, const ushort* __restrict__ Bt,
    const float* __restrict__ bias, void* __restrict__ Cv, void* __restrict__ Cv2,
    int M, int N, int K, int mode,
    const float* __restrict__ xc, const float* __restrict__ ca,
    const float* __restrict__ cb, const float* __restrict__ lk)
{
    __shared__ ushort As[64*64];   // [64 m][64 k], XOR-swizzled: byte ^= (row&7)<<4
    __shared__ ushort Bs[64*64];
    int tid = threadIdx.x, lane = tid & 63, w = tid >> 6;
    int wm = w >> 1, wn = w & 1;
    int m0 = blockIdx.y * 64, n0 = blockIdx.x * 64;
    int col = lane & 15, grp = lane >> 4;
    f32x4 acc[2][2] = {};

    for (int k0 = 0; k0 < K; k0 += 64) {
        __syncthreads();
        #pragma unroll
        for (int s = 0; s < 2; ++s) {
            int i = tid + s*256;
            int r = i >> 3, j = i & 7;
            int kb = (j*16) ^ ((r & 7) << 4);    // pre-swizzled source byte offset
            gload16((const char*)(A  + (size_t)(m0 + r)*K + k0) + kb,
                    (char*)As + s*4096 + w*1024);
            gload16((const char*)(Bt + (size_t)(n0 + r)*K + k0) + kb,
                    (char*)Bs + s*4096 + w*1024);
        }
        __syncthreads();
        #pragma unroll
        for (int kk = 0; kk < 64; kk += 32) {
            short8 a[2], b[2];
            #pragma unroll
            for (int f = 0; f < 2; ++f) {
                int ra = wm*32 + f*16 + col;
                a[f] = *(const short8*)((char*)As + ra*128 + (((kk + grp*8)*2) ^ ((ra & 7) << 4)));
                int rb = wn*32 + f*16 + col;
                b[f] = *(const short8*)((char*)Bs + rb*128 + (((kk + grp*8)*2) ^ ((rb & 7) << 4)));
            }
            #pragma unroll
            for (int fm = 0; fm < 2; ++fm)
                #pragma unroll
                for (int fn = 0; fn < 2; ++fn)
                    acc[fm][fn] = __builtin_amdgcn_mfma_f32_16x16x32_bf16(a[fm], b[fn], acc[fm][fn], 0, 0, 0);
        }
    }
    float kap = (mode == 5) ? log1pf(expf(lk[0])) : 0.f;
    #pragma unroll
    for (int fm = 0; fm < 2; ++fm) {
        #pragma unroll
        for (int fn = 0; fn < 2; ++fn) {
            int ncol = n0 + wn*32 + fn*16 + col;
            int mbase = m0 + wm*32 + fm*16 + grp*4;
            float bs = bias[ncol];
            if (mode == 4 && ncol >= 512) {          // Vt transposed
                ushort* base = (ushort*)Cv2 - (size_t)512*M;
                ushort4 u;
                u.x = f2bf(acc[fm][fn][0] + bs); u.y = f2bf(acc[fm][fn][1] + bs);
                u.z = f2bf(acc[fm][fn][2] + bs); u.w = f2bf(acc[fm][fn][3] + bs);
                *(ushort4*)(base + (size_t)ncol*M + mbase) = u;
            } else if (mode == 4) {                  // Q (scaled) / K head-major
                int cc = ncol & 255, hh = cc >> 5, hd = cc & 31;
                ushort* base = (ushort*)Cv + ((ncol < 256) ? 0u : 1048576u);
                float sc = (ncol < 256) ? QSCALE : 1.f;
                #pragma unroll
                for (int r = 0; r < 4; ++r)
                    base[((size_t)hh*M + mbase + r)*HDIM + hd] = f2bf((acc[fm][fn][r] + bs) * sc);
            } else if (mode == 5) {                  // decorator epilogue
                #pragma unroll
                for (int r = 0; r < 4; ++r) {
                    int m = mbase + r;
                    float basev = (m < NC_) ? ca[(size_t)m*DD + ncol]
                                            : cb[(size_t)(m - NC_)*DD + ncol];
                    float wv = 0.f;
                    if (m < NC_) { float e = xc[m]; wv = e / (e + kap); }
                    float v = basev + wv * (acc[fm][fn][r] + bs);
                    ((float*)Cv)[(size_t)m*DD + ncol] = v;
                    ((ushort*)Cv2)[(size_t)m*DD + ncol] = f2bf(v);
                }
            } else {
                #pragma unroll
                for (int r = 0; r < 4; ++r) {
                    float v = acc[fm][fn][r] + bs;
                    if (mode == 3) v = fmaxf(v, 0.f);
                    if (mode == 0) ((float*)Cv)[(size_t)(mbase + r)*N + ncol] = v;
                    else           ((ushort*)Cv)[(size_t)(mbase + r)*N + ncol] = f2bf(v);
                }
            }
        }
    }
}

// ---------------- flash attention: 16 waves, 64 q/block, 128-key tiles ----------------
// No-max softmax (p = exp2(s) directly). K/V via global_load_lds, rule-#21 both-sides
// swizzle. P stays in registers; TRUNCATING bf16 P-pack (2 ops/pair; bias cancels in
// O = sum(PV)/sum(P) since lsum is the ones-MFMA over the SAME truncated pf).
// 2x-unrolled tile loop with compile-time buffer selection. lsum via ones-MFMA.
__global__ __launch_bounds__(1024, 8) void attn_kernel(
    const ushort* __restrict__ Qh, const ushort* __restrict__ Kh,
    const ushort* __restrict__ Vt, ushort* __restrict__ AO,
    float* __restrict__ pml, float* __restrict__ pacc, int l2mode)
{
    __shared__ __align__(16) char smem[37888];   // K0@0 K1@8192 V0@16384 V1@24576; cacc overlay
    __shared__ float cml[16][16];
    int tid = threadIdx.x;
    int w = tid >> 6, lane = tid & 63;
    int q = lane & 15, g = lane >> 4;
    int wq = w & 3, kh = w >> 2;
    int h = blockIdx.y;
    int zb = blockIdx.z;
    int q0   = l2mode ? (NC_ + blockIdx.x * 64) : (blockIdx.x * 64);
    int kbeg = l2mode ? zb * 1536 : 0;
    int do_self = l2mode ? (zb == 0) : (q0 >= NC_);
    int nt = l2mode ? 12 : (((q0 >= NC_) ? NC_ : NTOK) >> 7);   // 12/24/32: always even

    // Q B-frag (pre-scaled, head-major)
    short8 bq = *(const short8*)&Qh[((size_t)h*NTOK + q0 + wq*16 + q)*HDIM + g*8];
    short8 ones;
    #pragma unroll
    for (int e = 0; e < 8; ++e) ones[e] = (short)0x3F80;   // bf16(1.0)

    f32x4 acc0 = {0.f,0.f,0.f,0.f}, acc1 = {0.f,0.f,0.f,0.f};
    f32x4 accl = {0.f,0.f,0.f,0.f};
    const f32x4 z = {0.f,0.f,0.f,0.f};

    // ---- staging source (per-lane, inverse-permuted + pre-swizzled) ----
    const ushort* src0;
    char *dst0, *dst1;
    size_t sstep;
    if (w < 8) {        // K: wave w stages lines w*8..w*8+7 (1KB)
        int L  = (w << 3) + (lane >> 3);
        int s  = lane & 7;
        int e  = s ^ (L & 7);
        int r  = 2*L + (e >> 2);         // physical key-row 0..127
        int qt = e & 3;
        int ch = r >> 5, rr = r & 31;
        int hi = (rr >> 4) & 1, qp = rr & 15;
        int key = ch*32 + (((qp >> 2) << 3) | (hi << 2) | (qp & 3));   // inverse perm
        src0 = Kh + ((size_t)h*NTOK + kbeg + key)*HDIM + qt*8;
        sstep = (size_t)128*HDIM;
        dst0 = smem + w*1024;
        dst1 = dst0 + 8192;
    } else {            // V: wave u stages rows u*4..u*4+3 (1KB)
        int u = w - 8;
        int d = u*4 + (lane >> 4);
        int s = lane & 15;
        int e = (s & 8) | ((s ^ (d & 7)) & 7);
        src0 = Vt + ((size_t)(h*HDIM + d))*NTOK + kbeg + e*8;
        sstep = 128;
        dst0 = smem + 16384 + u*1024;
        dst1 = dst0 + 8192;
    }
    gload16(src0, dst0);                 // tile 0
    asm volatile("s_waitcnt vmcnt(0)" ::: "memory");
    __builtin_amdgcn_s_barrier();
    __builtin_amdgcn_sched_barrier(0);

    // ---- compute read pointers (swizzled) ----
    const int L0 = kh*16 + (q >> 1);
    const char* kb0 = smem + L0*128 + (((((q & 1) << 2) + g) ^ (L0 & 7)) << 4);
    const int vslot = (kh << 2) + g;
    const int vsx = (vslot & 8) | ((vslot ^ (q & 7)) & 7);
    const char* vb0 = smem + 16384 + q*256 + (vsx << 4);
    const char* vb1 = vb0 + 16*256;

    // one tile: BUF is a literal 0/1 (static buffer selection), TT the tile index
#define ATTN_TILE(BUF, TT)                                                               \
    {                                                                                    \
        if ((TT) + 1 < nt)                                                               \
            gload16(src0 + (size_t)((TT)+1)*sstep, (BUF) ? dst0 : dst1);                 \
        short8 ka0 = *(const short8*)(kb0 + (BUF)*8192);                                 \
        short8 ka1 = *(const short8*)(kb0 + (BUF)*8192 + 1024);                          \
        __builtin_amdgcn_s_setprio(1);                                                   \
        f32x4 st0 = __builtin_amdgcn_mfma_f32_16x16x32_bf16(ka0, bq, z, 0, 0, 0);        \
        f32x4 st1 = __builtin_amdgcn_mfma_f32_16x16x32_bf16(ka1, bq, z, 0, 0, 0);        \
        __builtin_amdgcn_s_setprio(0);                                                   \
        float p0 = EXP2(st0[0]), p1 = EXP2(st0[1]);                                      \
        float p2 = EXP2(st0[2]), p3 = EXP2(st0[3]);                                      \
        float p4 = EXP2(st1[0]), p5 = EXP2(st1[1]);                                      \
        float p6 = EXP2(st1[2]), p7 = EXP2(st1[3]);                                      \
        uint4 pw;                                                                        \
        pw.x = (__float_as_uint(p0) >> 16) | (__float_as_uint(p1) & 0xFFFF0000u);        \
        pw.y = (__float_as_uint(p2) >> 16) | (__float_as_uint(p3) & 0xFFFF0000u);        \
        pw.z = (__float_as_uint(p4) >> 16) | (__float_as_uint(p5) & 0xFFFF0000u);        \
        pw.w = (__float_as_uint(p6) >> 16) | (__float_as_uint(p7) & 0xFFFF0000u);        \
        short8 pf = *(short8*)&pw;                                                       \
        short8 va0 = *(const short8*)(vb0 + (BUF)*8192);                                 \
        short8 va1 = *(const short8*)(vb1 + (BUF)*8192);                                 \
        __builtin_amdgcn_s_setprio(1);                                                   \
        acc0 = __builtin_amdgcn_mfma_f32_16x16x32_bf16(va0, pf, acc0, 0, 0, 0);          \
        acc1 = __builtin_amdgcn_mfma_f32_16x16x32_bf16(va1, pf, acc1, 0, 0, 0);          \
        accl = __builtin_amdgcn_mfma_f32_16x16x32_bf16(ones, pf, accl, 0, 0, 0);         \
        __builtin_amdgcn_s_setprio(0);                                                   \
        if ((TT) + 1 < nt) {                                                             \
            asm volatile("s_waitcnt vmcnt(0)" ::: "memory");                             \
            __builtin_amdgcn_s_barrier();                                                \
            __builtin_amdgcn_sched_barrier(0);                                           \
        }                                                                                \
    }

    for (int t = 0; t < nt; t += 2) {   // nt always even
        ATTN_TILE(0, t)
        ATTN_TILE(1, t + 1)
    }
#undef ATTN_TILE

    float lsum = accl[0];   // full sum over this wave's keys (cross-group via MFMA)

    if (do_self && kh == 0) {   // self-key (structural mask), once per query
        int qg = q0 + wq*16 + q;
        short8 kv = *(const short8*)&Kh[((size_t)h*NTOK + qg)*HDIM + g*8];
        float d8 = 0.f;
        #pragma unroll
        for (int e = 0; e < 8; ++e) d8 += bf2f((ushort)bq[e]) * bf2f((ushort)kv[e]);
        d8 += __shfl_xor(d8, 16, 64);
        d8 += __shfl_xor(d8, 32, 64);    // already log2-scaled (Q pre-scaled)
        float pp = EXP2(d8);
        lsum += pp;
        #pragma unroll
        for (int r = 0; r < 4; ++r) {
            acc0[r] += pp * bf2f(Vt[(size_t)(h*HDIM + g*4 + r)*NTOK + qg]);
            acc1[r] += pp * bf2f(Vt[(size_t)(h*HDIM + 16 + g*4 + r)*NTOK + qg]);
        }
    }

    __syncthreads();                      // K/V tiles dead; reuse smem as combine buffer
    float* cacc = (float*)smem;           // [16][32][17]
    #pragma unroll
    for (int r = 0; r < 4; ++r) {
        cacc[(w*32 + g*4 + r)*17 + q]      = acc0[r];
        cacc[(w*32 + 16 + g*4 + r)*17 + q] = acc1[r];
    }
    if (g == 0) cml[w][q] = lsum;
    __syncthreads();

    if (w < 4) {   // merge over key-quarters {w, w+4, w+8, w+12}; q-group w (plain sums)
        float L = cml[w][q] + cml[w+4][q] + cml[w+8][q] + cml[w+12][q];
        if (!l2mode) {
            float inv = 1.f / L;
            ushort* dst = AO + (size_t)(q0 + w*16 + q)*DD + h*HDIM;
            ushort4 o0, o1;
            #pragma unroll
            for (int r = 0; r < 4; ++r) {
                int e0 = g*4 + r, e1 = 16 + g*4 + r;
                float O0 = cacc[(w*32+e0)*17+q] + cacc[((w+4)*32+e0)*17+q]
                         + cacc[((w+8)*32+e0)*17+q] + cacc[((w+12)*32+e0)*17+q];
                float O1 = cacc[(w*32+e1)*17+q] + cacc[((w+4)*32+e1)*17+q]
                         + cacc[((w+8)*32+e1)*17+q] + cacc[((w+12)*32+e1)*17+q];
                ((ushort*)&o0)[r] = f2bf(O0 * inv);
                ((ushort*)&o1)[r] = f2bf(O1 * inv);
            }
            *(ushort4*)(dst + g*4) = o0;
            *(ushort4*)(dst + 16 + g*4) = o1;
        } else {     // partial out: unnormalized O + l
            int qi = q0 - NC_ + w*16 + q;
            float* pa = pacc + (((size_t)zb*NH + h)*NT_ + qi)*32;
            #pragma unroll
            for (int r = 0; r < 4; ++r) {
                int e0 = g*4 + r, e1 = 16 + g*4 + r;
                pa[e0] = cacc[(w*32+e0)*17+q] + cacc[((w+4)*32+e0)*17+q]
                       + cacc[((w+8)*32+e0)*17+q] + cacc[((w+12)*32+e0)*17+q];
                pa[e1] = cacc[(w*32+e1)*17+q] + cacc[((w+4)*32+e1)*17+q]
                       + cacc[((w+8)*32+e1)*17+q] + cacc[((w+12)*32+e1)*17+q];
            }
            if (g == 0) pml[((size_t)zb*NH + h)*NT_ + qi] = L;
        }
    }
}

// ---------------- combine: merge of layer-2 attn partials -> AO (plain sums) ----------------
__global__ __launch_bounds__(256) void combine_kernel(
    const float* __restrict__ pml, const float* __restrict__ pacc, ushort* __restrict__ AO)
{
    int item = blockIdx.x * 8 + (threadIdx.x >> 5);   // 8192 items = 8 h x 1024 q
    int d = threadIdx.x & 31;
    int hh = item >> 10, qi = item & 1023;
    size_t i0 = ((size_t)0*NH + hh)*NT_ + qi;
    size_t i1 = ((size_t)1*NH + hh)*NT_ + qi;
    float inv = 1.f / (pml[i0] + pml[i1]);
    float O = pacc[i0*32 + d] + pacc[i1*32 + d];
    AO[(size_t)(NC_ + qi)*DD + hh*HDIM + d] = f2bf(O * inv);
}

// ---------------- layernorm: c = LN(c + delta)*g + b ; + bf16 copy; optional head ----
__global__ __launch_bounds__(256) void ln_kernel(
    float* __restrict__ c, const float* __restrict__ delta,
    const float* __restrict__ g, const float* __restrict__ b, ushort* __restrict__ cbf,
    const float* __restrict__ ow, const float* __restrict__ ob,
    const float* __restrict__ expo, float* __restrict__ out)
{
    int tid = threadIdx.x;
    int wid = tid >> 6, lane = tid & 63;
    int row = blockIdx.x * 4 + wid;
    float4 x  = *(const float4*)&c[(size_t)row*DD + lane*4];
    float4 dl = *(const float4*)&delta[(size_t)row*DD + lane*4];
    x.x += dl.x; x.y += dl.y; x.z += dl.z; x.w += dl.w;
    float s = x.x + x.y + x.z + x.w;
    #pragma unroll
    for (int off = 1; off < 64; off <<= 1) s += __shfl_xor(s, off, 64);
    float mean = s * (1.f/DD);
    float dx = x.x-mean, dy = x.y-mean, dz = x.z-mean, dw = x.w-mean;
    float v = dx*dx + dy*dy + dz*dz + dw*dw;
    #pragma unroll
    for (int off = 1; off < 64; off <<= 1) v += __shfl_xor(v, off, 64);
    float rstd = rsqrtf(v*(1.f/DD) + 1e-5f);
    float4 g4 = *(const float4*)&g[lane*4];
    float4 b4 = *(const float4*)&b[lane*4];
    float4 o;
    o.x = dx*rstd*g4.x + b4.x;
    o.y = dy*rstd*g4.y + b4.y;
    o.z = dz*rstd*g4.z + b4.z;
    o.w = dw*rstd*g4.w + b4.w;
    *(float4*)&c[(size_t)row*DD + lane*4] = o;
    ushort4 u;
    u.x = f2bf(o.x); u.y = f2bf(o.y); u.z = f2bf(o.z); u.w = f2bf(o.w);
    *(ushort4*)&cbf[(size_t)row*DD + lane*4] = u;
    if (ow != nullptr) {   // fused output head (target rows, local indexing)
        float4 wv = *(const float4*)&ow[lane*4];
        float ss = o.x*wv.x + o.y*wv.y + o.z*wv.z + o.w*wv.w;
        #pragma unroll
        for (int off = 1; off < 64; off <<= 1) ss += __shfl_xor(ss, off, 64);
        if (lane == 0) out[row] = expf(ss + ob[0]) * expo[row];
    }
}

extern "C" void kernel_launch(void* const* d_in, const int* in_sizes, int n_in,
                              void* d_out, int out_size, void* d_ws, size_t ws_size,
                              hipStream_t stream) {
    const float* c_ctx            = (const float*)d_in[0];
    const float* c_tgt            = (const float*)d_in[1];
    const float* y_context        = (const float*)d_in[2];
    const float* exposure_context = (const float*)d_in[3];
    const float* exposure_target  = (const float*)d_in[4];
    const float* dec_W1           = (const float*)d_in[5];
    const float* dec_b1           = (const float*)d_in[6];
    const float* dec_W2           = (const float*)d_in[7];
    const float* dec_b2           = (const float*)d_in[8];
    const float* log_kappa        = (const float*)d_in[9];
    const float* WQ               = (const float*)d_in[10];
    const float* bQ               = (const float*)d_in[11];
    const float* WK               = (const float*)d_in[12];
    const float* bK               = (const float*)d_in[13];
    const float* WV               = (const float*)d_in[14];
    const float* bV               = (const float*)d_in[15];
    const float* WO               = (const float*)d_in[16];
    const float* bO               = (const float*)d_in[17];
    const float* ln1_g            = (const float*)d_in[18];
    const float* ln1_b            = (const float*)d_in[19];
    const float* ln2_g            = (const float*)d_in[20];
    const float* ln2_b            = (const float*)d_in[21];
    const float* ffn_W1           = (const float*)d_in[22];
    const float* ffn_b1           = (const float*)d_in[23];
    const float* ffn_W2           = (const float*)d_in[24];
    const float* ffn_b2           = (const float*)d_in[25];
    const float* out_W            = (const float*)d_in[26];
    const float* out_b            = (const float*)d_in[27];
    float* out = (float*)d_out;

    float* ws = (float*)d_ws;
    float*  c    = ws;                          // 4096*256 f32
    float*  T    = ws + 1048576;                // 4096*256 f32 (also attn-L2 partial scratch)
    ushort* ub   = (ushort*)(ws + 2097152);
    ushort* c_bf = ub;                          // 4096*256 bf16
    ushort* Qh   = ub + 1048576;                // [8][4096][32] bf16, pre-scaled
    ushort* Khb  = ub + 2097152;                // [8][4096][32] bf16
    ushort* Vt   = ub + 3145728;                // [256][4096] bf16 (V transposed)
    ushort* AO   = ub + 4194304;                // 4096*256 bf16
    ushort* wbf  = ub + 5242880;                // 2*786432 bf16 weights + dec_W2t 65536
    ushort* wdec = wbf + 1572864;               // dec_W2t [256][256]
    float*  bqkv = (float*)(ub + 6881280);      // 2*768 f32
    ushort* tv   = AO;                          // 4096*256 bf16, dead after gemm5
    ushort* Hd   = Qh;                          // aliases Qh.. (dead then)
    float*  pml  = T;                           // [2][8][1024] f32
    float*  pacc = T + 16384;                   // [2][8][1024][32] f32

    convert_kernel<<<dim3(4355, 2), 256, 0, stream>>>(WQ, WK, WV, WO, ffn_W1, ffn_W2,
                                                      bQ, bK, bV, dec_W2,
                                                      y_context, dec_W1, dec_b1, tv,
                                                      wbf, bqkv);
    gemm_bf<<<dim3(4, 64), 256, 0, stream>>>(tv, wdec, dec_b2, c, c_bf, NTOK, DD, DD, 5,
                                             exposure_context, c_ctx, c_tgt, log_kappa);
    // ---- layer 0 (full 4096 rows) ----
    {
        ushort* wl = wbf;
        gemm_bf<<<dim3(12, 64), 256, 0, stream>>>(c_bf, wl, bqkv, Qh, Vt, NTOK, 768, DD, 4,
                                                  nullptr, nullptr, nullptr, nullptr);
        attn_kernel<<<dim3(64, NH, 1), 1024, 0, stream>>>(Qh, Khb, Vt, AO, nullptr, nullptr, 0);
        gemm_bf<<<dim3(4, 64),  256, 0, stream>>>(AO, wl + 196608, bO, T, nullptr, NTOK, DD, DD, 0,
                                                  nullptr, nullptr, nullptr, nullptr);
        ln_kernel<<<NTOK/4, 256, 0, stream>>>(c, T, ln1_g, ln1_b, c_bf,
                                              nullptr, nullptr, nullptr, nullptr);
        gemm_bf<<<dim3(16, 64), 256, 0, stream>>>(c_bf, wl + 262144, ffn_b1, Hd, nullptr, NTOK, FFD, DD, 3,
                                                  nullptr, nullptr, nullptr, nullptr);
        gemm_bf<<<dim3(4, 64),  256, 0, stream>>>(Hd, wl + 524288, ffn_b2, T, nullptr, NTOK, DD, FFD, 0,
                                                  nullptr, nullptr, nullptr, nullptr);
        ln_kernel<<<NTOK/4, 256, 0, stream>>>(c, T, ln2_g, ln2_b, c_bf,
                                              nullptr, nullptr, nullptr, nullptr);
    }
    // ---- layer 1 (target rows only after QKV) ----
    {
        ushort* wl = wbf + 786432;
        gemm_bf<<<dim3(12, 64), 256, 0, stream>>>(c_bf, wl, bqkv + 768, Qh, Vt, NTOK, 768, DD, 4,
                                                  nullptr, nullptr, nullptr, nullptr);
        attn_kernel<<<dim3(16, NH, 2), 1024, 0, stream>>>(Qh, Khb, Vt, AO, pml, pacc, 1);
        combine_kernel<<<1024, 256, 0, stream>>>(pml, pacc, AO);
        gemm_bf<<<dim3(4, 16),  256, 0, stream>>>(AO + (size_t)NC_*DD, wl + 196608, bO + DD, T, nullptr,
                                                  NT_, DD, DD, 0, nullptr, nullptr, nullptr, nullptr);
        ln_kernel<<<NT_/4, 256, 0, stream>>>(c + (size_t)NC_*DD, T, ln1_g + DD, ln1_b + DD,
                                             c_bf + (size_t)NC_*DD,
                                             nullptr, nullptr, nullptr, nullptr);
        gemm_bf<<<dim3(16, 16), 256, 0, stream>>>(c_bf + (size_t)NC_*DD, wl + 262144, ffn_b1 + FFD,
                                                  Hd, nullptr, NT_, FFD, DD, 3,
                                                  nullptr, nullptr, nullptr, nullptr);
        gemm_bf<<<dim3(4, 16),  256, 0, stream>>>(Hd, wl + 524288, ffn_b2 + DD, T, nullptr,
                                                  NT_, DD, FFD, 0, nullptr, nullptr, nullptr, nullptr);
        ln_kernel<<<NT_/4, 256, 0, stream>>>(c + (size_t)NC_*DD, T, ln2_g + DD, ln2_b + DD,
                                             c_bf + (size_t)NC_*DD,
                                             out_W, out_b, exposure_target, out);
    }
}